// Round 3
// baseline (11051.722 us; speedup 1.0000x reference)
//
#include <hip/hip_runtime.h>
#include <math.h>

#define NG 360
#define NV 100
#define ND 32
#define NU 512
#define NT 15
#define NVOC 5000
#define NH 8
#define NE 544
#define NHD 68
#define OFF_SCORES 4800000
#define INV_SQRT_HD 0.12126781f
#define CS_SCALE 43.65636f
#define PBLK 192   // persistent kernel blocks (24 per sub-counter x 8)

__device__ __forceinline__ float leaky(float x) { return x >= 0.f ? x : 0.2f * x; }
__device__ __forceinline__ float sigm(float x) { return 1.f / (1.f + expf(-x)); }
__device__ __forceinline__ float bf2f(unsigned short u) { return __uint_as_float(((unsigned)u) << 16); }
__device__ __forceinline__ unsigned short f2bf(float x) {
    unsigned b = __float_as_uint(x);
    return (unsigned short)((b + 0x7FFFu + ((b >> 16) & 1u)) >> 16);
}

// Two-level grid barrier. bar[sub*16] are 8 sub-counters (64B apart), bar[128] master.
// Monotone counters (no reset): barrier #k waits master >= 8*k.
__device__ __forceinline__ void gbar(unsigned* bar, unsigned k) {
    __syncthreads();
    if (threadIdx.x == 0) {
        __threadfence();
        unsigned* sub = bar + ((blockIdx.x & 7) << 4);
        unsigned* mst = bar + 128;
        if (atomicAdd(sub, 1u) == k * 24u - 1u)
            atomicAdd(mst, 1u);
        while (__hip_atomic_load(mst, __ATOMIC_ACQUIRE, __HIP_MEMORY_SCOPE_AGENT) < k * 8u)
            __builtin_amdgcn_s_sleep(2);
        __threadfence();
    }
    __syncthreads();
}

// ---------- Precompute ----------

__global__ void k_transpose_feat(const float* __restrict__ features, float* __restrict__ fX) {
    __shared__ float tile[64 * 65];
    int c0 = (int)blockIdx.x * 64;
    int tl = (int)threadIdx.x;
    int c = tl & 63, q0 = tl >> 6;
    for (int i = 0; i < 16; ++i) {
        int b = q0 + (i << 2);
        int col = c0 + c;
        float v = (col < NG * NV) ? features[b * (NG * NV) + col] : 0.f;
        tile[c * 65 + b] = v;
    }
    __syncthreads();
    int b2 = tl & 63, cr = tl >> 6;
    for (int i = 0; i < 16; ++i) {
        int c2 = cr + (i << 2);
        int col = c0 + c2;
        if (col < NG * NV) fX[col * 64 + b2] = tile[c2 * 65 + b2];
    }
}

__global__ __launch_bounds__(256) void k_encoder2(
        const float* __restrict__ fX, const float* __restrict__ enc_W,
        const float* __restrict__ enc_b, const float* __restrict__ enc_g,
        const float* __restrict__ enc_beta, float* __restrict__ featT) {
    __shared__ float fxs[6400];
    __shared__ float ps[256], pq[256];
    int g = (int)blockIdx.x, tid = (int)threadIdx.x;
    #pragma unroll
    for (int k = 0; k < 25; ++k) fxs[tid + k * 256] = fX[g * 6400 + tid + k * 256];
    __syncthreads();
    int lane = tid & 63, w = tid >> 6, d0 = w * 8;
    float acc[8];
    #pragma unroll
    for (int j = 0; j < 8; ++j) acc[j] = enc_b[g * 32 + d0 + j];
    const float* wb = enc_W + g * 3200 + d0 * 100;
    #pragma unroll 4
    for (int v = 0; v < 100; ++v) {
        float fv = fxs[v * 64 + lane];
        #pragma unroll
        for (int j = 0; j < 8; ++j) acc[j] += fv * wb[j * 100 + v];
    }
    float sm = 0.f, sq = 0.f;
    #pragma unroll
    for (int j = 0; j < 8; ++j) { sm += acc[j]; sq += acc[j] * acc[j]; }
    ps[tid] = sm; pq[tid] = sq;
    __syncthreads();
    float m = (ps[lane] + ps[64 + lane] + ps[128 + lane] + ps[192 + lane]) * (1.f / 32.f);
    float q = (pq[lane] + pq[64 + lane] + pq[128 + lane] + pq[192 + lane]);
    float var = q * (1.f / 32.f) - m * m;
    float rstd = 1.f / sqrtf(var + 1e-5f);
    #pragma unroll
    for (int j = 0; j < 8; ++j) {
        int d = d0 + j;
        float x = (acc[j] - m) * rstd * enc_g[d] + enc_beta[d];
        featT[(g * 32 + d) * 64 + lane] = leaky(x);
    }
}

__global__ void k_init_state(const float* __restrict__ a0, const float* __restrict__ c0,
                             float* __restrict__ aT0, float* __restrict__ cT) {
    __shared__ float tile[64 * 65];
    int which = (int)blockIdx.x >> 3;
    int t0 = ((int)blockIdx.x & 7) * 64;
    const float* src = which ? c0 : a0;
    int tl = (int)threadIdx.x;
    int c = tl & 63, q0 = tl >> 6;
    for (int i = 0; i < 16; ++i) {
        int b = q0 + (i << 2);
        tile[c * 65 + b] = src[b * NU + t0 + c];
    }
    __syncthreads();
    int b2 = tl & 63, cr = tl >> 6;
    for (int i = 0; i < 16; ++i) {
        int c2 = cr + (i << 2);
        float v = tile[c2 * 65 + b2];
        int idx = (t0 + c2) * 64 + b2;
        if (which) cT[idx] = v;
        else aT0[idx] = v;
    }
}

__global__ void k_embed(const int* __restrict__ text, const float* __restrict__ emb,
                        float* __restrict__ xT) {
    int t = (int)blockIdx.x;
    int tl = (int)threadIdx.x;
    int b = tl & 63, uq = tl >> 6;
    int row = text[b * NT + t];
    const float* er = emb + (long)row * NU;
    float* dst = xT + t * NU * 64;
    for (int i = 0; i < 128; ++i) {
        int u = uq + (i << 2);
        dst[u * 64 + b] = er[u];
    }
}

__global__ void k_kf(const float* __restrict__ featT, const float* __restrict__ in_w,
                     unsigned short* __restrict__ kfT) {
    int wid = __builtin_amdgcn_readfirstlane((int)blockIdx.x * 4 + ((int)threadIdx.x >> 6));
    int lane = (int)threadIdx.x & 63;
    int j = wid / 34, et = wid % 34;
    if (j >= NG) return;
    int e0 = et * 16;
    float acc[16];
    #pragma unroll
    for (int jj = 0; jj < 16; ++jj) acc[jj] = 0.f;
    const float* ft = featT + j * ND * 64 + lane;
    const float* wr0 = in_w + (NE + e0) * NE;
    #pragma unroll 4
    for (int d = 0; d < ND; ++d) {
        float fv = ft[d * 64];
        #pragma unroll
        for (int jj = 0; jj < 16; ++jj) acc[jj] += fv * wr0[jj * NE + d];
    }
    unsigned short* dst = kfT + (j * NE + e0) * 64 + lane;
    #pragma unroll
    for (int jj = 0; jj < 16; ++jj) dst[jj * 64] = f2bf(acc[jj]);
}

__global__ void k_featmean(const float* __restrict__ featT, float* __restrict__ fmean) {
    int wid = __builtin_amdgcn_readfirstlane((int)blockIdx.x * 4 + ((int)threadIdx.x >> 6));
    int lane = (int)threadIdx.x & 63;
    if (wid >= ND) return;
    float s = 0.f;
    for (int g = 0; g < NG; ++g) s += featT[(g * ND + wid) * 64 + lane];
    fmean[wid * 64 + lane] = s * (1.f / 360.f);
}

__global__ void k_qmean(const float* __restrict__ fmean, const float* __restrict__ in_w,
                        float* __restrict__ qmean) {
    int wid = __builtin_amdgcn_readfirstlane((int)blockIdx.x * 4 + ((int)threadIdx.x >> 6));
    int lane = (int)threadIdx.x & 63;
    if (wid >= 68) return;
    int e0 = wid * 8;
    float acc[8];
    #pragma unroll
    for (int jj = 0; jj < 8; ++jj) acc[jj] = 0.f;
    #pragma unroll 4
    for (int d = 0; d < ND; ++d) {
        float fv = fmean[d * 64 + lane];
        #pragma unroll
        for (int jj = 0; jj < 8; ++jj) acc[jj] += fv * in_w[(e0 + jj) * NE + d];
    }
    #pragma unroll
    for (int jj = 0; jj < 8; ++jj) qmean[(e0 + jj) * 64 + lane] = acc[jj];
}

__global__ void k_cs(const float* __restrict__ qmean, const unsigned short* __restrict__ kfT,
                     float* __restrict__ cS) {
    int wid = __builtin_amdgcn_readfirstlane((int)blockIdx.x * 4 + ((int)threadIdx.x >> 6));
    int lane = (int)threadIdx.x & 63;
    if (wid >= 720) return;
    int h = wid / 90, jt = wid % 90, j0 = jt * 4;
    float acc[4] = {0.f, 0.f, 0.f, 0.f};
    const float* qm = qmean + (h * NHD) * 64 + lane;
    const unsigned short* kb = kfT + (j0 * NE + h * NHD) * 64 + lane;
    #pragma unroll 4
    for (int d = 0; d < NHD; ++d) {
        float qv = qm[d * 64];
        #pragma unroll
        for (int jj = 0; jj < 4; ++jj) acc[jj] += qv * bf2f(kb[(jj * NE + d) * 64]);
    }
    #pragma unroll
    for (int jj = 0; jj < 4; ++jj) cS[(h * NG + j0 + jj) * 64 + lane] = acc[jj] * CS_SCALE;
}

__global__ __launch_bounds__(256) void k_gihx(const float* __restrict__ xT,
                                              const float* __restrict__ Wih,
                                              float* __restrict__ gihxAll) {
    int wid = __builtin_amdgcn_readfirstlane((int)blockIdx.x * 4 + ((int)threadIdx.x >> 6));
    int lane = (int)threadIdx.x & 63;
    int t = wid >> 8;
    int r = (wid & 255) * 8;
    const float* xb = xT + t * NU * 64;
    const float* wb = Wih + r * NE + ND;
    float acc[8];
    #pragma unroll
    for (int j = 0; j < 8; ++j) acc[j] = 0.f;
    #pragma unroll 4
    for (int k = 0; k < NU; ++k) {
        float xv = xb[k * 64 + lane];
        #pragma unroll
        for (int j = 0; j < 8; ++j) acc[j] += xv * wb[j * NE + k];
    }
    float* dst = gihxAll + t * (4 * NU * 64) + r * 64 + lane;
    #pragma unroll
    for (int j = 0; j < 8; ++j) dst[j * 64] = acc[j];
}

// ---------- Persistent recurrence kernel ----------
// 192 blocks x 256. Per step: A(qa+ghh+zero ctx) | B(v+partials) | C(W+ctx) | F(gates+h+LN).
__global__ __launch_bounds__(256) void k_loop(
        unsigned* __restrict__ bar,
        const float* __restrict__ aT0, float* __restrict__ cT,
        const float* __restrict__ in_w, const float* __restrict__ in_b,
        const float* __restrict__ Whh, const float* __restrict__ Wih,
        const float* __restrict__ bih, const float* __restrict__ bhh,
        const float* __restrict__ ln_g, const float* __restrict__ ln_b,
        const unsigned short* __restrict__ kfT, const float* __restrict__ cS,
        const float* __restrict__ featT, const float* __restrict__ gihxAll,
        float* __restrict__ qaT, float* __restrict__ ghh,
        float* __restrict__ vT, float* __restrict__ sevP, float* __restrict__ cevP,
        float* __restrict__ ctx, float* __restrict__ wT,
        float* __restrict__ hTall, float* __restrict__ lnPS, float* __restrict__ lnPQ) {
    __shared__ float lds[4096];
    int blk = (int)blockIdx.x, tid = (int)threadIdx.x;
    int lane = tid & 63, wv = tid >> 6;
    int wid = __builtin_amdgcn_readfirstlane(blk * 4 + wv);
    unsigned bk = 0;

    for (int t = 0; t < NT; ++t) {
        // ---- Phase A ----
        if (wid < 648) {
            float rstd = 1.f, mneg = 0.f;
            const float* src = aT0;
            if (t > 0) {
                const float* pS = lnPS + (size_t)(t - 1) * 2048;
                const float* pQ = lnPQ + (size_t)(t - 1) * 2048;
                float ms = 0.f, qs = 0.f;
                #pragma unroll 8
                for (int i = 0; i < 32; ++i) { ms += pS[i * 64 + lane]; qs += pQ[i * 64 + lane]; }
                float m = ms * (1.f / 512.f);
                float var = qs * (1.f / 512.f) - m * m;
                rstd = 1.f / sqrtf(var + 1e-5f);
                mneg = -m * rstd;
                src = hTall + (size_t)(t - 1) * (NU * 64);
            }
            float acc[4] = {0.f, 0.f, 0.f, 0.f};
            const float* wb; int stride; 
            int n0;
            if (wid < 136) { n0 = wid * 4; wb = in_w + n0 * NE + ND; stride = NE; }
            else { n0 = (wid - 136) * 4; wb = Whh + n0 * NU; stride = NU; }
            if (t == 0) {
                #pragma unroll 4
                for (int k = 0; k < NU; ++k) {
                    float av = src[k * 64 + lane];
                    #pragma unroll
                    for (int j = 0; j < 4; ++j) acc[j] += av * wb[j * stride + k];
                }
            } else {
                #pragma unroll 4
                for (int k = 0; k < NU; ++k) {
                    float hv = src[k * 64 + lane];
                    float av = fmaf(fmaf(hv, rstd, mneg), ln_g[k], ln_b[k]);
                    #pragma unroll
                    for (int j = 0; j < 4; ++j) acc[j] += av * wb[j * stride + k];
                }
            }
            if (wid < 136) {
                #pragma unroll
                for (int j = 0; j < 4; ++j) qaT[(n0 + j) * 64 + lane] = acc[j] + in_b[n0 + j];
            } else {
                #pragma unroll
                for (int j = 0; j < 4; ++j) ghh[(n0 + j) * 64 + lane] = acc[j];
            }
        } else if (wid < 656) {
            int base = (wid - 648) * 256;
            #pragma unroll
            for (int i = 0; i < 4; ++i) ctx[base + i * 64 + lane] = 0.f;
        }
        gbar(bar, ++bk);

        // ---- Phase B: v + exp partials ----
        if (wid < 720) {
            int h = wid / 90, jt = wid % 90, j0 = jt * 4;
            float acc[4] = {0.f, 0.f, 0.f, 0.f};
            const float* qm = qaT + (h * NHD) * 64 + lane;
            const unsigned short* kb = kfT + (j0 * NE + h * NHD) * 64 + lane;
            #pragma unroll 4
            for (int d = 0; d < NHD; ++d) {
                float qv = qm[d * 64];
                #pragma unroll
                for (int j = 0; j < 4; ++j) acc[j] += qv * bf2f(kb[(j * NE + d) * 64]);
            }
            float eS = 0.f, eC = 0.f;
            #pragma unroll
            for (int j = 0; j < 4; ++j) {
                float v = acc[j] * INV_SQRT_HD;
                vT[(h * NG + j0 + j) * 64 + lane] = v;
                float e = expf(v);
                float c = cS[(h * NG + j0 + j) * 64 + lane];
                eS += e; eC += c * e;
            }
            sevP[wid * 64 + lane] = eS;
            cevP[wid * 64 + lane] = eC;
        }
        gbar(bar, ++bk);

        // ---- Phase C: blocks 0..7 ----
        if (blk < 8) {
            float* SevL = lds; float* CevL = lds + 512; float* Wl = lds + 1024;
            for (int hh = wv; hh < 8; hh += 4) {
                float a = 0.f, c = 0.f;
                for (int jt = 0; jt < 90; ++jt) {
                    a += sevP[(hh * 90 + jt) * 64 + lane];
                    c += cevP[(hh * 90 + jt) * 64 + lane];
                }
                SevL[hh * 64 + lane] = a;
                CevL[hh * 64 + lane] = c;
            }
            __syncthreads();
            float invS[8], cevM[8];
            #pragma unroll
            for (int hh = 0; hh < 8; ++hh) {
                float iv = 1.f / SevL[hh * 64 + lane];
                invS[hh] = iv;
                cevM[hh] = CevL[hh * 64 + lane] * iv;
            }
            int j0 = blk * 45;
            float* wDst = wT + (size_t)t * NG * 64;
            for (int jj = wv; jj < 45; jj += 4) {
                int j = j0 + jj;
                float acc = 0.f;
                #pragma unroll
                for (int hh = 0; hh < 8; ++hh) {
                    float v = vT[(hh * NG + j) * 64 + lane];
                    float e = expf(v);
                    float c = cS[(hh * NG + j) * 64 + lane];
                    acc += e * invS[hh] * (1.f + (c - cevM[hh]) * (1.f / 360.f));
                }
                float W = acc * 0.125f;
                Wl[jj * 64 + lane] = W;
                wDst[j * 64 + lane] = W;
            }
            __syncthreads();
            int d0 = wv * 8;
            float acc[8];
            #pragma unroll
            for (int dd = 0; dd < 8; ++dd) acc[dd] = 0.f;
            for (int jj = 0; jj < 45; ++jj) {
                float wvv = Wl[jj * 64 + lane];
                const float* fb = featT + ((size_t)(j0 + jj) * ND + d0) * 64 + lane;
                #pragma unroll
                for (int dd = 0; dd < 8; ++dd) acc[dd] += wvv * fb[dd * 64];
            }
            #pragma unroll
            for (int dd = 0; dd < 8; ++dd) atomicAdd(&ctx[(d0 + dd) * 64 + lane], acc[dd]);
        }
        gbar(bar, ++bk);

        // ---- Phase F: blocks 0..31, 16 u per block ----
        if (blk < 32) {
            float* rS = lds; float* rQ = lds + 512;
            float cx[32];
            #pragma unroll 8
            for (int d = 0; d < 32; ++d) cx[d] = ctx[d * 64 + lane];
            const float* gx = gihxAll + (size_t)t * (4 * NU * 64);
            float* hDst = hTall + (size_t)t * (NU * 64);
            int u0 = blk * 16 + wv * 4;
            float ssum = 0.f, qsum = 0.f;
            for (int i = 0; i < 4; ++i) {
                int u = u0 + i;
                float g4[4];
                #pragma unroll
                for (int q = 0; q < 4; ++q) {
                    int n = q * NU + u;
                    float gv = gx[n * 64 + lane] + ghh[n * 64 + lane] + bih[n] + bhh[n];
                    const float* wr = Wih + n * NE;
                    #pragma unroll
                    for (int d = 0; d < 32; ++d) gv += cx[d] * wr[d];
                    g4[q] = gv;
                }
                float ig = sigm(g4[0]), fg = sigm(g4[1]), gg = tanhf(g4[2]), og = sigm(g4[3]);
                float cn = fg * cT[u * 64 + lane] + ig * gg;
                cT[u * 64 + lane] = cn;
                float hv = og * tanhf(cn);
                hDst[u * 64 + lane] = hv;
                ssum += hv; qsum += hv * hv;
            }
            rS[tid] = ssum; rQ[tid] = qsum;
            __syncthreads();
            if (tid < 64) {
                lnPS[((size_t)t * 32 + blk) * 64 + tid] =
                    rS[tid] + rS[64 + tid] + rS[128 + tid] + rS[192 + tid];
                lnPQ[((size_t)t * 32 + blk) * 64 + tid] =
                    rQ[tid] + rQ[64 + tid] + rQ[128 + tid] + rQ[192 + tid];
            }
        }
        gbar(bar, ++bk);
    }
}

// ---------- Post-loop head ----------

// sTall[t][k][b] = leaky((h-m)*rstd*g+b); 120 blocks (t, slice of 64 k)
__global__ __launch_bounds__(256) void kS(const float* __restrict__ hTall,
                                          const float* __restrict__ lnPS, const float* __restrict__ lnPQ,
                                          const float* __restrict__ ln_g, const float* __restrict__ ln_b,
                                          float* __restrict__ sTall) {
    int bid = (int)blockIdx.x, tid = (int)threadIdx.x;
    int t = bid >> 3, sl = bid & 7;
    int lane = tid & 63, w = tid >> 6;
    const float* pS = lnPS + (size_t)t * 2048;
    const float* pQ = lnPQ + (size_t)t * 2048;
    float ms = 0.f, qs = 0.f;
    #pragma unroll 8
    for (int i = 0; i < 32; ++i) { ms += pS[i * 64 + lane]; qs += pQ[i * 64 + lane]; }
    float m = ms * (1.f / 512.f);
    float var = qs * (1.f / 512.f) - m * m;
    float rstd = 1.f / sqrtf(var + 1e-5f);
    for (int i = 0; i < 16; ++i) {
        int k = sl * 64 + w * 16 + i;
        float hv = hTall[((size_t)t * NU + k) * 64 + lane];
        float av = fmaf((hv - m) * rstd, ln_g[k], ln_b[k]);
        sTall[((size_t)t * NU + k) * 64 + lane] = leaky(av);
    }
}

// h1All: 960 waves (t, group of 4 rows)
__global__ __launch_bounds__(256) void kHead1(const float* __restrict__ sTall,
                                              const float* __restrict__ W1, const float* __restrict__ b1,
                                              float* __restrict__ h1All) {
    int wid = __builtin_amdgcn_readfirstlane((int)blockIdx.x * 4 + ((int)threadIdx.x >> 6));
    int lane = (int)threadIdx.x & 63;
    int t = wid >> 6, ng = wid & 63, n0 = ng * 4;
    const float* sb = sTall + (size_t)t * NU * 64;
    const float* wb = W1 + n0 * NU;
    float acc[4] = {0.f, 0.f, 0.f, 0.f};
    #pragma unroll 4
    for (int k = 0; k < NU; ++k) {
        float sv = sb[k * 64 + lane];
        #pragma unroll
        for (int j = 0; j < 4; ++j) acc[j] += sv * wb[j * NU + k];
    }
    float* dst = h1All + ((size_t)t * 256 + n0) * 64 + lane;
    #pragma unroll
    for (int j = 0; j < 4; ++j) dst[j * 64] = leaky(acc[j] + b1[n0 + j]);
}

// logits + per-unit exp partials: 18750 units (t, 4 vocab rows)
__global__ __launch_bounds__(256) void kLogits(const float* __restrict__ h1All,
                                               const float* __restrict__ W2, const float* __restrict__ b2,
                                               float* __restrict__ lgAll, float* __restrict__ zPart) {
    int wid = __builtin_amdgcn_readfirstlane((int)blockIdx.x * 4 + ((int)threadIdx.x >> 6));
    int lane = (int)threadIdx.x & 63;
    if (wid >= 18750) return;
    int t = wid / 1250, nl = wid % 1250, n0 = nl * 4;
    const float* hb = h1All + (size_t)t * 256 * 64;
    const float* wb = W2 + n0 * 256;
    float acc[4] = {0.f, 0.f, 0.f, 0.f};
    #pragma unroll 4
    for (int k = 0; k < 256; ++k) {
        float hv = hb[k * 64 + lane];
        #pragma unroll
        for (int j = 0; j < 4; ++j) acc[j] += hv * wb[j * 256 + k];
    }
    float eS = 0.f;
    float* dst = lgAll + ((size_t)t * NVOC + n0) * 64 + lane;
    #pragma unroll
    for (int j = 0; j < 4; ++j) {
        float lg = acc[j] + b2[n0 + j];
        dst[j * 64] = lg;
        eS += expf(lg);
    }
    zPart[(size_t)wid * 64 + lane] = eS;
}

// combine exp partials: 60 blocks (t, quarter)
__global__ __launch_bounds__(256) void kZc(const float* __restrict__ zPart, float* __restrict__ zQ) {
    __shared__ float red[256];
    int bid = (int)blockIdx.x, tid = (int)threadIdx.x;
    int t = bid >> 2, qd = bid & 3;
    int lane = tid & 63, w = tid >> 6;
    float p = 0.f;
    for (int i = w; i < 313; i += 4) {
        int u = qd * 313 + i;
        if (u < 1250) p += zPart[((size_t)t * 1250 + u) * 64 + lane];
    }
    red[tid] = p;
    __syncthreads();
    if (tid < 64) zQ[bid * 64 + tid] = red[tid] + red[64 + tid] + red[128 + tid] + red[192 + tid];
}

// softmax scale + transpose to out[b][t][n]
__global__ __launch_bounds__(256) void kOut(const float* __restrict__ lgAll,
                                            const float* __restrict__ zQ, float* __restrict__ out) {
    __shared__ float tile[64 * 65];
    int bid = (int)blockIdx.x;
    int t = bid / 79, nt = bid % 79;
    int n0 = nt * 64;
    int tid = (int)threadIdx.x, lane = tid & 63, w = tid >> 6;
    const float* lg = lgAll + (size_t)t * (NVOC * 64);
    float z = zQ[(t * 4) * 64 + lane] + zQ[(t * 4 + 1) * 64 + lane] +
              zQ[(t * 4 + 2) * 64 + lane] + zQ[(t * 4 + 3) * 64 + lane];
    float invZ = 1.f / z;
    for (int i = 0; i < 16; ++i) {
        int r = w * 16 + i, n = n0 + r;
        if (n < NVOC) tile[r * 65 + lane] = expf(lg[n * 64 + lane]) * invZ;
    }
    __syncthreads();
    for (int i = 0; i < 16; ++i) {
        int b = w * 16 + i;
        int n = n0 + lane;
        if (n < NVOC) out[(size_t)b * (NT * NVOC) + t * NVOC + n] = tile[lane * 65 + b];
    }
}

__global__ __launch_bounds__(256) void kScoresT(const float* __restrict__ wT, float* __restrict__ out) {
    __shared__ float tile[64 * 65];
    int bid = (int)blockIdx.x;
    int t = bid / 6, jt = bid % 6;
    int j0 = jt * 64;
    int tid = (int)threadIdx.x, lane = tid & 63, w = tid >> 6;
    for (int i = 0; i < 16; ++i) {
        int r = w * 16 + i, j = j0 + r;
        if (j < NG) tile[r * 65 + lane] = wT[(size_t)t * (NG * 64) + j * 64 + lane];
    }
    __syncthreads();
    for (int i = 0; i < 16; ++i) {
        int b = w * 16 + i;
        int j = j0 + lane;
        if (j < NG) out[OFF_SCORES + (size_t)b * (NT * NG) + t * NG + j] = tile[lane * 65 + b];
    }
}

// ---------- Launch ----------
extern "C" void kernel_launch(void* const* d_in, const int* in_sizes, int n_in,
                              void* d_out, int out_size, void* d_ws, size_t ws_size,
                              hipStream_t stream) {
    const float* features = (const float*)d_in[0];
    const int*   text     = (const int*)d_in[1];
    const float* a0       = (const float*)d_in[2];
    const float* c0       = (const float*)d_in[3];
    const float* enc_W    = (const float*)d_in[4];
    const float* enc_b    = (const float*)d_in[5];
    const float* enc_g    = (const float*)d_in[6];
    const float* enc_beta = (const float*)d_in[7];
    const float* emb      = (const float*)d_in[8];
    const float* in_w     = (const float*)d_in[9];
    const float* in_b     = (const float*)d_in[10];
    const float* Wih      = (const float*)d_in[11];
    const float* Whh      = (const float*)d_in[12];
    const float* bih      = (const float*)d_in[13];
    const float* bhh      = (const float*)d_in[14];
    const float* ln_g     = (const float*)d_in[15];
    const float* ln_b     = (const float*)d_in[16];
    const float* W1       = (const float*)d_in[17];
    const float* b1       = (const float*)d_in[18];
    const float* W2       = (const float*)d_in[19];
    const float* b2       = (const float*)d_in[20];
    float* out = (float*)d_out;

    unsigned* bar = (unsigned*)d_ws;
    float* ws = (float*)d_ws + 256;
    size_t off = 0;
    auto alloc = [&](size_t n) { float* p = ws + off; off += (n + 63) & ~(size_t)63; return p; };
    float* lgAll   = alloc((size_t)NT * NVOC * 64);   // aliased as fX pre-loop
    float* fX      = lgAll;
    float* featT   = alloc((size_t)NG * ND * 64);
    float* xT      = alloc((size_t)NT * NU * 64);
    float* gihxAll = alloc((size_t)NT * 4 * NU * 64);
    float* kfTf    = alloc((size_t)NG * NE * 64 / 2 + 64);
    unsigned short* kfTu = (unsigned short*)kfTf;
    float* wT      = alloc((size_t)NT * NG * 64);
    float* vT      = alloc((size_t)NH * NG * 64);
    float* cS      = alloc((size_t)NH * NG * 64);
    float* fmean   = alloc((size_t)ND * 64);
    float* qmean   = alloc((size_t)NE * 64);
    float* aT0     = alloc((size_t)NU * 64);
    float* cT_     = alloc((size_t)NU * 64);
    float* hTall   = alloc((size_t)NT * NU * 64);
    float* sTall   = alloc((size_t)NT * NU * 64);
    float* h1All   = alloc((size_t)NT * 256 * 64);
    float* qaT     = alloc((size_t)NE * 64);
    float* ghh     = alloc((size_t)4 * NU * 64);
    float* sevP    = alloc((size_t)720 * 64);
    float* cevP    = alloc((size_t)720 * 64);
    float* ctx     = alloc((size_t)ND * 64);
    float* lnPS    = alloc((size_t)NT * 32 * 64);
    float* lnPQ    = alloc((size_t)NT * 32 * 64);
    float* zPart   = alloc((size_t)NT * 1250 * 64);
    float* zQ      = alloc((size_t)NT * 4 * 64);

    hipMemsetAsync(bar, 0, 1024, stream);

    k_transpose_feat<<<563, 256, 0, stream>>>(features, fX);
    k_encoder2<<<NG, 256, 0, stream>>>(fX, enc_W, enc_b, enc_g, enc_beta, featT);
    k_init_state<<<16, 256, 0, stream>>>(a0, c0, aT0, cT_);
    k_embed<<<NT, 256, 0, stream>>>(text, emb, xT);
    k_kf<<<3060, 256, 0, stream>>>(featT, in_w, kfTu);
    k_featmean<<<8, 256, 0, stream>>>(featT, fmean);
    k_qmean<<<17, 256, 0, stream>>>(fmean, in_w, qmean);
    k_cs<<<180, 256, 0, stream>>>(qmean, kfTu, cS);
    k_gihx<<<960, 256, 0, stream>>>(xT, Wih, gihxAll);

    k_loop<<<PBLK, 256, 0, stream>>>(bar, aT0, cT_, in_w, in_b, Whh, Wih, bih, bhh,
                                     ln_g, ln_b, kfTu, cS, featT, gihxAll,
                                     qaT, ghh, vT, sevP, cevP, ctx, wT,
                                     hTall, lnPS, lnPQ);

    kS<<<120, 256, 0, stream>>>(hTall, lnPS, lnPQ, ln_g, ln_b, sTall);
    kHead1<<<240, 256, 0, stream>>>(sTall, W1, b1, h1All);
    kLogits<<<4688, 256, 0, stream>>>(h1All, W2, b2, lgAll, zPart);
    kZc<<<60, 256, 0, stream>>>(zPart, zQ);
    kOut<<<NT * 79, 256, 0, stream>>>(lgAll, zQ, out);
    kScoresT<<<NT * 6, 256, 0, stream>>>(wT, out);
}

// Round 4
// 1916.583 us; speedup vs baseline: 5.7664x; 5.7664x over previous
//
#include <hip/hip_runtime.h>
#include <math.h>

#define NG 360
#define NV 100
#define ND 32
#define NU 512
#define NT 15
#define NVOC 5000
#define NH 8
#define NE 544
#define NHD 68
#define OFF_SCORES 4800000
#define INV_SQRT_HD 0.12126781f
#define CS_SCALE 43.65636f

__device__ __forceinline__ float leaky(float x) { return x >= 0.f ? x : 0.2f * x; }
__device__ __forceinline__ float sigm(float x) { return 1.f / (1.f + expf(-x)); }
__device__ __forceinline__ float bf2f(unsigned short u) { return __uint_as_float(((unsigned)u) << 16); }
__device__ __forceinline__ unsigned short f2bf(float x) {
    unsigned b = __float_as_uint(x);
    return (unsigned short)((b + 0x7FFFu + ((b >> 16) & 1u)) >> 16);
}

// ---------- Precompute ----------

__global__ void k_transpose_feat(const float* __restrict__ features, float* __restrict__ fX) {
    __shared__ float tile[64 * 65];
    int c0 = (int)blockIdx.x * 64;
    int tl = (int)threadIdx.x;
    int c = tl & 63, q0 = tl >> 6;
    for (int i = 0; i < 16; ++i) {
        int b = q0 + (i << 2);
        int col = c0 + c;
        float v = (col < NG * NV) ? features[b * (NG * NV) + col] : 0.f;
        tile[c * 65 + b] = v;
    }
    __syncthreads();
    int b2 = tl & 63, cr = tl >> 6;
    for (int i = 0; i < 16; ++i) {
        int c2 = cr + (i << 2);
        int col = c0 + c2;
        if (col < NG * NV) fX[col * 64 + b2] = tile[c2 * 65 + b2];
    }
}

__global__ __launch_bounds__(256) void k_encoder2(
        const float* __restrict__ fX, const float* __restrict__ enc_W,
        const float* __restrict__ enc_b, const float* __restrict__ enc_g,
        const float* __restrict__ enc_beta, float* __restrict__ featT) {
    __shared__ float fxs[6400];
    __shared__ float ps[256], pq[256];
    int g = (int)blockIdx.x, tid = (int)threadIdx.x;
    #pragma unroll
    for (int k = 0; k < 25; ++k) fxs[tid + k * 256] = fX[g * 6400 + tid + k * 256];
    __syncthreads();
    int lane = tid & 63, w = tid >> 6, d0 = w * 8;
    float acc[8];
    #pragma unroll
    for (int j = 0; j < 8; ++j) acc[j] = enc_b[g * 32 + d0 + j];
    const float* wb = enc_W + g * 3200 + d0 * 100;
    #pragma unroll 4
    for (int v = 0; v < 100; ++v) {
        float fv = fxs[v * 64 + lane];
        #pragma unroll
        for (int j = 0; j < 8; ++j) acc[j] += fv * wb[j * 100 + v];
    }
    float sm = 0.f, sq = 0.f;
    #pragma unroll
    for (int j = 0; j < 8; ++j) { sm += acc[j]; sq += acc[j] * acc[j]; }
    ps[tid] = sm; pq[tid] = sq;
    __syncthreads();
    float m = (ps[lane] + ps[64 + lane] + ps[128 + lane] + ps[192 + lane]) * (1.f / 32.f);
    float q = (pq[lane] + pq[64 + lane] + pq[128 + lane] + pq[192 + lane]);
    float var = q * (1.f / 32.f) - m * m;
    float rstd = 1.f / sqrtf(var + 1e-5f);
    #pragma unroll
    for (int j = 0; j < 8; ++j) {
        int d = d0 + j;
        float x = (acc[j] - m) * rstd * enc_g[d] + enc_beta[d];
        featT[(g * 32 + d) * 64 + lane] = leaky(x);
    }
}

__global__ void k_init_state(const float* __restrict__ a0, const float* __restrict__ c0,
                             float* __restrict__ aT0, float* __restrict__ cT) {
    __shared__ float tile[64 * 65];
    int which = (int)blockIdx.x >> 3;
    int t0 = ((int)blockIdx.x & 7) * 64;
    const float* src = which ? c0 : a0;
    int tl = (int)threadIdx.x;
    int c = tl & 63, q0 = tl >> 6;
    for (int i = 0; i < 16; ++i) {
        int b = q0 + (i << 2);
        tile[c * 65 + b] = src[b * NU + t0 + c];
    }
    __syncthreads();
    int b2 = tl & 63, cr = tl >> 6;
    for (int i = 0; i < 16; ++i) {
        int c2 = cr + (i << 2);
        float v = tile[c2 * 65 + b2];
        int idx = (t0 + c2) * 64 + b2;
        if (which) cT[idx] = v;
        else aT0[idx] = v;
    }
}

__global__ void k_embed(const int* __restrict__ text, const float* __restrict__ emb,
                        float* __restrict__ xT) {
    int t = (int)blockIdx.x;
    int tl = (int)threadIdx.x;
    int b = tl & 63, uq = tl >> 6;
    int row = text[b * NT + t];
    const float* er = emb + (long)row * NU;
    float* dst = xT + t * NU * 64;
    for (int i = 0; i < 128; ++i) {
        int u = uq + (i << 2);
        dst[u * 64 + b] = er[u];
    }
}

__global__ void k_kf(const float* __restrict__ featT, const float* __restrict__ in_w,
                     unsigned short* __restrict__ kfT) {
    int wid = __builtin_amdgcn_readfirstlane((int)blockIdx.x * 4 + ((int)threadIdx.x >> 6));
    int lane = (int)threadIdx.x & 63;
    int j = wid / 34, et = wid % 34;
    if (j >= NG) return;
    int e0 = et * 16;
    float acc[16];
    #pragma unroll
    for (int jj = 0; jj < 16; ++jj) acc[jj] = 0.f;
    const float* ft = featT + j * ND * 64 + lane;
    const float* wr0 = in_w + (NE + e0) * NE;
    #pragma unroll 4
    for (int d = 0; d < ND; ++d) {
        float fv = ft[d * 64];
        #pragma unroll
        for (int jj = 0; jj < 16; ++jj) acc[jj] += fv * wr0[jj * NE + d];
    }
    unsigned short* dst = kfT + (j * NE + e0) * 64 + lane;
    #pragma unroll
    for (int jj = 0; jj < 16; ++jj) dst[jj * 64] = f2bf(acc[jj]);
}

__global__ void k_featmean(const float* __restrict__ featT, float* __restrict__ fmean) {
    int wid = __builtin_amdgcn_readfirstlane((int)blockIdx.x * 4 + ((int)threadIdx.x >> 6));
    int lane = (int)threadIdx.x & 63;
    if (wid >= ND) return;
    float s = 0.f;
    for (int g = 0; g < NG; ++g) s += featT[(g * ND + wid) * 64 + lane];
    fmean[wid * 64 + lane] = s * (1.f / 360.f);
}

__global__ void k_qmean(const float* __restrict__ fmean, const float* __restrict__ in_w,
                        float* __restrict__ qmean) {
    int wid = __builtin_amdgcn_readfirstlane((int)blockIdx.x * 4 + ((int)threadIdx.x >> 6));
    int lane = (int)threadIdx.x & 63;
    if (wid >= 68) return;
    int e0 = wid * 8;
    float acc[8];
    #pragma unroll
    for (int jj = 0; jj < 8; ++jj) acc[jj] = 0.f;
    #pragma unroll 4
    for (int d = 0; d < ND; ++d) {
        float fv = fmean[d * 64 + lane];
        #pragma unroll
        for (int jj = 0; jj < 8; ++jj) acc[jj] += fv * in_w[(e0 + jj) * NE + d];
    }
    #pragma unroll
    for (int jj = 0; jj < 8; ++jj) qmean[(e0 + jj) * 64 + lane] = acc[jj];
}

__global__ void k_cs(const float* __restrict__ qmean, const unsigned short* __restrict__ kfT,
                     float* __restrict__ cS) {
    int wid = __builtin_amdgcn_readfirstlane((int)blockIdx.x * 4 + ((int)threadIdx.x >> 6));
    int lane = (int)threadIdx.x & 63;
    if (wid >= 720) return;
    int h = wid / 90, jt = wid % 90, j0 = jt * 4;
    float acc[4] = {0.f, 0.f, 0.f, 0.f};
    const float* qm = qmean + (h * NHD) * 64 + lane;
    const unsigned short* kb = kfT + (j0 * NE + h * NHD) * 64 + lane;
    #pragma unroll 4
    for (int d = 0; d < NHD; ++d) {
        float qv = qm[d * 64];
        #pragma unroll
        for (int jj = 0; jj < 4; ++jj) acc[jj] += qv * bf2f(kb[(jj * NE + d) * 64]);
    }
    #pragma unroll
    for (int jj = 0; jj < 4; ++jj) cS[(h * NG + j0 + jj) * 64 + lane] = acc[jj] * CS_SCALE;
}

__global__ __launch_bounds__(256) void k_gihx(const float* __restrict__ xT,
                                              const float* __restrict__ Wih,
                                              float* __restrict__ gihxAll) {
    int wid = __builtin_amdgcn_readfirstlane((int)blockIdx.x * 4 + ((int)threadIdx.x >> 6));
    int lane = (int)threadIdx.x & 63;
    int t = wid >> 8;
    int r = (wid & 255) * 8;
    const float* xb = xT + t * NU * 64;
    const float* wb = Wih + r * NE + ND;
    float acc[8];
    #pragma unroll
    for (int j = 0; j < 8; ++j) acc[j] = 0.f;
    #pragma unroll 4
    for (int k = 0; k < NU; ++k) {
        float xv = xb[k * 64 + lane];
        #pragma unroll
        for (int j = 0; j < 8; ++j) acc[j] += xv * wb[j * NE + k];
    }
    float* dst = gihxAll + t * (4 * NU * 64) + r * 64 + lane;
    #pragma unroll
    for (int j = 0; j < 8; ++j) dst[j * 64] = acc[j];
}

// ---------- Per-step ----------

// 162 blocks: wid<136 qa rows, else ghh rows. LN of h(t-1) folded in.
__global__ __launch_bounds__(256) void kA(
        const float* __restrict__ aT0, const float* __restrict__ hTall,
        const float* __restrict__ lnPS, const float* __restrict__ lnPQ,
        const float* __restrict__ ln_g, const float* __restrict__ ln_b,
        const float* __restrict__ in_w, const float* __restrict__ in_b,
        const float* __restrict__ Whh,
        float* __restrict__ qaT, float* __restrict__ ghh, int t) {
    int wid = __builtin_amdgcn_readfirstlane((int)blockIdx.x * 4 + ((int)threadIdx.x >> 6));
    int lane = (int)threadIdx.x & 63;
    float rstd = 1.f, mneg = 0.f;
    const float* src = aT0;
    if (t > 0) {
        const float* pS = lnPS + (size_t)(t - 1) * 1024;
        const float* pQ = lnPQ + (size_t)(t - 1) * 1024;
        float ms = 0.f, qs = 0.f;
        #pragma unroll
        for (int i = 0; i < 16; ++i) { ms += pS[i * 64 + lane]; qs += pQ[i * 64 + lane]; }
        float m = ms * (1.f / 512.f);
        float var = qs * (1.f / 512.f) - m * m;
        rstd = 1.f / sqrtf(var + 1e-5f);
        mneg = -m * rstd;
        src = hTall + (size_t)(t - 1) * (NU * 64);
    }
    float acc[4] = {0.f, 0.f, 0.f, 0.f};
    const float* wb; int stride; int n0;
    if (wid < 136) { n0 = wid * 4; wb = in_w + n0 * NE + ND; stride = NE; }
    else { n0 = (wid - 136) * 4; wb = Whh + n0 * NU; stride = NU; }
    if (t == 0) {
        #pragma unroll 4
        for (int k = 0; k < NU; ++k) {
            float av = src[k * 64 + lane];
            #pragma unroll
            for (int j = 0; j < 4; ++j) acc[j] += av * wb[j * stride + k];
        }
    } else {
        #pragma unroll 4
        for (int k = 0; k < NU; ++k) {
            float hv = src[k * 64 + lane];
            float av = fmaf(fmaf(hv, rstd, mneg), ln_g[k], ln_b[k]);
            #pragma unroll
            for (int j = 0; j < 4; ++j) acc[j] += av * wb[j * stride + k];
        }
    }
    if (wid < 136) {
        #pragma unroll
        for (int j = 0; j < 4; ++j) qaT[(n0 + j) * 64 + lane] = acc[j] + in_b[n0 + j];
    } else {
        #pragma unroll
        for (int j = 0; j < 4; ++j) ghh[(n0 + j) * 64 + lane] = acc[j];
    }
}

// 180 blocks: v + exp partials.
__global__ __launch_bounds__(256) void kB(
        const float* __restrict__ qaT, const unsigned short* __restrict__ kfT,
        const float* __restrict__ cS,
        float* __restrict__ vT, float* __restrict__ sevP, float* __restrict__ cevP) {
    int wid = __builtin_amdgcn_readfirstlane((int)blockIdx.x * 4 + ((int)threadIdx.x >> 6));
    int lane = (int)threadIdx.x & 63;
    int h = wid / 90, jt = wid % 90, j0 = jt * 4;
    float acc[4] = {0.f, 0.f, 0.f, 0.f};
    const float* qm = qaT + (h * NHD) * 64 + lane;
    const unsigned short* kb = kfT + (j0 * NE + h * NHD) * 64 + lane;
    #pragma unroll 4
    for (int d = 0; d < NHD; ++d) {
        float qv = qm[d * 64];
        #pragma unroll
        for (int j = 0; j < 4; ++j) acc[j] += qv * bf2f(kb[(j * NE + d) * 64]);
    }
    float eS = 0.f, eC = 0.f;
    #pragma unroll
    for (int j = 0; j < 4; ++j) {
        float v = acc[j] * INV_SQRT_HD;
        vT[(h * NG + j0 + j) * 64 + lane] = v;
        float e = expf(v);
        float c = cS[(h * NG + j0 + j) * 64 + lane];
        eS += e; eC += c * e;
    }
    sevP[wid * 64 + lane] = eS;
    cevP[wid * 64 + lane] = eC;
}

// 8 blocks: combine partials, W + wT write + ctx partials.
__global__ __launch_bounds__(256) void kC(
        const float* __restrict__ vT, const float* __restrict__ cS,
        const float* __restrict__ sevP, const float* __restrict__ cevP,
        const float* __restrict__ featT,
        float* __restrict__ wDst, float* __restrict__ ctxP) {
    __shared__ float SevL[512], CevL[512], Wl[45 * 64];
    int tid = (int)threadIdx.x, s = (int)blockIdx.x;
    int lane = tid & 63, w = tid >> 6;
    for (int hh = w; hh < 8; hh += 4) {
        float a = 0.f, c = 0.f;
        #pragma unroll 6
        for (int jt = 0; jt < 90; ++jt) {
            a += sevP[(hh * 90 + jt) * 64 + lane];
            c += cevP[(hh * 90 + jt) * 64 + lane];
        }
        SevL[hh * 64 + lane] = a;
        CevL[hh * 64 + lane] = c;
    }
    __syncthreads();
    float invS[8], cevM[8];
    #pragma unroll
    for (int hh = 0; hh < 8; ++hh) {
        float iv = 1.f / SevL[hh * 64 + lane];
        invS[hh] = iv;
        cevM[hh] = CevL[hh * 64 + lane] * iv;
    }
    int j0 = s * 45;
    for (int jj = w; jj < 45; jj += 4) {
        int j = j0 + jj;
        float acc = 0.f;
        #pragma unroll
        for (int hh = 0; hh < 8; ++hh) {
            float v = vT[(hh * NG + j) * 64 + lane];
            float e = expf(v);
            float c = cS[(hh * NG + j) * 64 + lane];
            acc += e * invS[hh] * (1.f + (c - cevM[hh]) * (1.f / 360.f));
        }
        float W = acc * 0.125f;
        Wl[jj * 64 + lane] = W;
        wDst[j * 64 + lane] = W;
    }
    __syncthreads();
    int d0 = w * 8;
    float acc[8];
    #pragma unroll
    for (int dd = 0; dd < 8; ++dd) acc[dd] = 0.f;
    for (int jj = 0; jj < 45; ++jj) {
        float wvv = Wl[jj * 64 + lane];
        const float* fb = featT + ((size_t)(j0 + jj) * ND + d0) * 64 + lane;
        #pragma unroll
        for (int dd = 0; dd < 8; ++dd) acc[dd] += wvv * fb[dd * 64];
    }
    #pragma unroll
    for (int dd = 0; dd < 8; ++dd) ctxP[s * 2048 + (d0 + dd) * 64 + lane] = acc[dd];
}

// 16 blocks (32 u each): gates + cell + h + LN partials.
__global__ __launch_bounds__(256) void kF1(
        const float* __restrict__ gihxT, const float* __restrict__ ghh,
        const float* __restrict__ ctxP, const float* __restrict__ Wih,
        const float* __restrict__ bih, const float* __restrict__ bhh,
        float* __restrict__ cT, float* __restrict__ hDst,
        float* __restrict__ lnPS, float* __restrict__ lnPQ) {
    __shared__ float ctxL[2048];
    __shared__ float rS[256], rQ[256];
    int tid = (int)threadIdx.x, bid = (int)blockIdx.x;
    #pragma unroll
    for (int k = 0; k < 8; ++k) {
        int idx = tid + k * 256;
        float s = 0.f;
        #pragma unroll
        for (int sl = 0; sl < 8; ++sl) s += ctxP[sl * 2048 + idx];
        ctxL[idx] = s;
    }
    __syncthreads();
    int lane = tid & 63, w = tid >> 6;
    float cx[32];
    #pragma unroll 8
    for (int d = 0; d < 32; ++d) cx[d] = ctxL[d * 64 + lane];
    int u0 = bid * 32 + w * 8;
    float ssum = 0.f, qsum = 0.f;
    for (int i = 0; i < 8; ++i) {
        int u = u0 + i;
        float g4[4];
        #pragma unroll
        for (int q = 0; q < 4; ++q) {
            int n = q * NU + u;
            float gv = gihxT[n * 64 + lane] + ghh[n * 64 + lane] + bih[n] + bhh[n];
            const float* wr = Wih + n * NE;
            #pragma unroll
            for (int d = 0; d < 32; ++d) gv += cx[d] * wr[d];
            g4[q] = gv;
        }
        float ig = sigm(g4[0]), fg = sigm(g4[1]), gg = tanhf(g4[2]), og = sigm(g4[3]);
        float cn = fg * cT[u * 64 + lane] + ig * gg;
        cT[u * 64 + lane] = cn;
        float hv = og * tanhf(cn);
        hDst[u * 64 + lane] = hv;
        ssum += hv; qsum += hv * hv;
    }
    rS[tid] = ssum; rQ[tid] = qsum;
    __syncthreads();
    if (tid < 64) {
        lnPS[bid * 64 + tid] = rS[tid] + rS[64 + tid] + rS[128 + tid] + rS[192 + tid];
        lnPQ[bid * 64 + tid] = rQ[tid] + rQ[64 + tid] + rQ[128 + tid] + rQ[192 + tid];
    }
}

// ---------- Post-loop head ----------

// 120 blocks (t, slice of 64 k): s = leaky(LN(h))
__global__ __launch_bounds__(256) void kS(const float* __restrict__ hTall,
                                          const float* __restrict__ lnPS, const float* __restrict__ lnPQ,
                                          const float* __restrict__ ln_g, const float* __restrict__ ln_b,
                                          float* __restrict__ sTall) {
    int bid = (int)blockIdx.x, tid = (int)threadIdx.x;
    int t = bid >> 3, sl = bid & 7;
    int lane = tid & 63, w = tid >> 6;
    const float* pS = lnPS + (size_t)t * 1024;
    const float* pQ = lnPQ + (size_t)t * 1024;
    float ms = 0.f, qs = 0.f;
    #pragma unroll
    for (int i = 0; i < 16; ++i) { ms += pS[i * 64 + lane]; qs += pQ[i * 64 + lane]; }
    float m = ms * (1.f / 512.f);
    float var = qs * (1.f / 512.f) - m * m;
    float rstd = 1.f / sqrtf(var + 1e-5f);
    for (int i = 0; i < 16; ++i) {
        int k = sl * 64 + w * 16 + i;
        float hv = hTall[((size_t)t * NU + k) * 64 + lane];
        float av = fmaf((hv - m) * rstd, ln_g[k], ln_b[k]);
        sTall[((size_t)t * NU + k) * 64 + lane] = leaky(av);
    }
}

// 240 blocks (960 waves): h1 for all t
__global__ __launch_bounds__(256) void kHead1(const float* __restrict__ sTall,
                                              const float* __restrict__ W1, const float* __restrict__ b1,
                                              float* __restrict__ h1All) {
    int wid = __builtin_amdgcn_readfirstlane((int)blockIdx.x * 4 + ((int)threadIdx.x >> 6));
    int lane = (int)threadIdx.x & 63;
    int t = wid >> 6, ng = wid & 63, n0 = ng * 4;
    const float* sb = sTall + (size_t)t * NU * 64;
    const float* wb = W1 + n0 * NU;
    float acc[4] = {0.f, 0.f, 0.f, 0.f};
    #pragma unroll 4
    for (int k = 0; k < NU; ++k) {
        float sv = sb[k * 64 + lane];
        #pragma unroll
        for (int j = 0; j < 4; ++j) acc[j] += sv * wb[j * NU + k];
    }
    float* dst = h1All + ((size_t)t * 256 + n0) * 64 + lane;
    #pragma unroll
    for (int j = 0; j < 4; ++j) dst[j * 64] = leaky(acc[j] + b1[n0 + j]);
}

// 4688 blocks: logits + per-wave exp partials
__global__ __launch_bounds__(256) void kLogits(const float* __restrict__ h1All,
                                               const float* __restrict__ W2, const float* __restrict__ b2,
                                               float* __restrict__ lgAll, float* __restrict__ zPart) {
    int wid = __builtin_amdgcn_readfirstlane((int)blockIdx.x * 4 + ((int)threadIdx.x >> 6));
    int lane = (int)threadIdx.x & 63;
    if (wid >= 18750) return;
    int t = wid / 1250, nl = wid % 1250, n0 = nl * 4;
    const float* hb = h1All + (size_t)t * 256 * 64;
    const float* wb = W2 + n0 * 256;
    float acc[4] = {0.f, 0.f, 0.f, 0.f};
    #pragma unroll 4
    for (int k = 0; k < 256; ++k) {
        float hv = hb[k * 64 + lane];
        #pragma unroll
        for (int j = 0; j < 4; ++j) acc[j] += hv * wb[j * 256 + k];
    }
    float eS = 0.f;
    float* dst = lgAll + ((size_t)t * NVOC + n0) * 64 + lane;
    #pragma unroll
    for (int j = 0; j < 4; ++j) {
        float lg = acc[j] + b2[n0 + j];
        dst[j * 64] = lg;
        eS += expf(lg);
    }
    zPart[(size_t)wid * 64 + lane] = eS;
}

// 60 blocks: combine exp partials (pure loads)
__global__ __launch_bounds__(256) void kZc(const float* __restrict__ zPart, float* __restrict__ zQ) {
    __shared__ float red[256];
    int bid = (int)blockIdx.x, tid = (int)threadIdx.x;
    int t = bid >> 2, qd = bid & 3;
    int lane = tid & 63, w = tid >> 6;
    float p = 0.f;
    for (int i = w; i < 313; i += 4) {
        int u = qd * 313 + i;
        if (u < 1250) p += zPart[((size_t)t * 1250 + u) * 64 + lane];
    }
    red[tid] = p;
    __syncthreads();
    if (tid < 64) zQ[bid * 64 + tid] = red[tid] + red[64 + tid] + red[128 + tid] + red[192 + tid];
}

__global__ __launch_bounds__(256) void kOut(const float* __restrict__ lgAll,
                                            const float* __restrict__ zQ, float* __restrict__ out) {
    __shared__ float tile[64 * 65];
    int bid = (int)blockIdx.x;
    int t = bid / 79, nt = bid % 79;
    int n0 = nt * 64;
    int tid = (int)threadIdx.x, lane = tid & 63, w = tid >> 6;
    const float* lg = lgAll + (size_t)t * (NVOC * 64);
    float z = zQ[(t * 4) * 64 + lane] + zQ[(t * 4 + 1) * 64 + lane] +
              zQ[(t * 4 + 2) * 64 + lane] + zQ[(t * 4 + 3) * 64 + lane];
    float invZ = 1.f / z;
    for (int i = 0; i < 16; ++i) {
        int r = w * 16 + i, n = n0 + r;
        if (n < NVOC) tile[r * 65 + lane] = expf(lg[n * 64 + lane]) * invZ;
    }
    __syncthreads();
    for (int i = 0; i < 16; ++i) {
        int b = w * 16 + i;
        int n = n0 + lane;
        if (n < NVOC) out[(size_t)b * (NT * NVOC) + t * NVOC + n] = tile[lane * 65 + b];
    }
}

__global__ __launch_bounds__(256) void kScoresT(const float* __restrict__ wT, float* __restrict__ out) {
    __shared__ float tile[64 * 65];
    int bid = (int)blockIdx.x;
    int t = bid / 6, jt = bid % 6;
    int j0 = jt * 64;
    int tid = (int)threadIdx.x, lane = tid & 63, w = tid >> 6;
    for (int i = 0; i < 16; ++i) {
        int r = w * 16 + i, j = j0 + r;
        if (j < NG) tile[r * 65 + lane] = wT[(size_t)t * (NG * 64) + j * 64 + lane];
    }
    __syncthreads();
    for (int i = 0; i < 16; ++i) {
        int b = w * 16 + i;
        int j = j0 + lane;
        if (j < NG) out[OFF_SCORES + (size_t)b * (NT * NG) + t * NG + j] = tile[lane * 65 + b];
    }
}

// ---------- Launch ----------
extern "C" void kernel_launch(void* const* d_in, const int* in_sizes, int n_in,
                              void* d_out, int out_size, void* d_ws, size_t ws_size,
                              hipStream_t stream) {
    const float* features = (const float*)d_in[0];
    const int*   text     = (const int*)d_in[1];
    const float* a0       = (const float*)d_in[2];
    const float* c0       = (const float*)d_in[3];
    const float* enc_W    = (const float*)d_in[4];
    const float* enc_b    = (const float*)d_in[5];
    const float* enc_g    = (const float*)d_in[6];
    const float* enc_beta = (const float*)d_in[7];
    const float* emb      = (const float*)d_in[8];
    const float* in_w     = (const float*)d_in[9];
    const float* in_b     = (const float*)d_in[10];
    const float* Wih      = (const float*)d_in[11];
    const float* Whh      = (const float*)d_in[12];
    const float* bih      = (const float*)d_in[13];
    const float* bhh      = (const float*)d_in[14];
    const float* ln_g     = (const float*)d_in[15];
    const float* ln_b     = (const float*)d_in[16];
    const float* W1       = (const float*)d_in[17];
    const float* b1       = (const float*)d_in[18];
    const float* W2       = (const float*)d_in[19];
    const float* b2       = (const float*)d_in[20];
    float* out = (float*)d_out;

    float* ws = (float*)d_ws;
    size_t off = 0;
    auto alloc = [&](size_t n) { float* p = ws + off; off += (n + 63) & ~(size_t)63; return p; };
    float* lgAll   = alloc((size_t)NT * NVOC * 64);   // aliased as fX pre-loop
    float* fX      = lgAll;
    float* featT   = alloc((size_t)NG * ND * 64);
    float* xT      = alloc((size_t)NT * NU * 64);
    float* gihxAll = alloc((size_t)NT * 4 * NU * 64);
    float* kfTf    = alloc((size_t)NG * NE * 64 / 2 + 64);
    unsigned short* kfTu = (unsigned short*)kfTf;
    float* wT      = alloc((size_t)NT * NG * 64);
    float* vT      = alloc((size_t)NH * NG * 64);
    float* cS      = alloc((size_t)NH * NG * 64);
    float* fmean   = alloc((size_t)ND * 64);
    float* qmean   = alloc((size_t)NE * 64);
    float* aT0     = alloc((size_t)NU * 64);
    float* cT_     = alloc((size_t)NU * 64);
    float* hTall   = alloc((size_t)NT * NU * 64);
    float* sTall   = alloc((size_t)NT * NU * 64);
    float* h1All   = alloc((size_t)NT * 256 * 64);
    float* qaT     = alloc((size_t)NE * 64);
    float* ghh     = alloc((size_t)4 * NU * 64);
    float* sevP    = alloc((size_t)720 * 64);
    float* cevP    = alloc((size_t)720 * 64);
    float* ctxP    = alloc((size_t)8 * ND * 64);
    float* lnPS    = alloc((size_t)NT * 16 * 64);
    float* lnPQ    = alloc((size_t)NT * 16 * 64);
    float* zPart   = alloc((size_t)NT * 1250 * 64);
    float* zQ      = alloc((size_t)NT * 4 * 64);

    k_transpose_feat<<<563, 256, 0, stream>>>(features, fX);
    k_encoder2<<<NG, 256, 0, stream>>>(fX, enc_W, enc_b, enc_g, enc_beta, featT);
    k_init_state<<<16, 256, 0, stream>>>(a0, c0, aT0, cT_);
    k_embed<<<NT, 256, 0, stream>>>(text, emb, xT);
    k_kf<<<3060, 256, 0, stream>>>(featT, in_w, kfTu);
    k_featmean<<<8, 256, 0, stream>>>(featT, fmean);
    k_qmean<<<17, 256, 0, stream>>>(fmean, in_w, qmean);
    k_cs<<<180, 256, 0, stream>>>(qmean, kfTu, cS);
    k_gihx<<<960, 256, 0, stream>>>(xT, Wih, gihxAll);

    for (int t = 0; t < NT; ++t) {
        kA<<<162, 256, 0, stream>>>(aT0, hTall, lnPS, lnPQ, ln_g, ln_b,
                                    in_w, in_b, Whh, qaT, ghh, t);
        kB<<<180, 256, 0, stream>>>(qaT, kfTu, cS, vT, sevP, cevP);
        kC<<<8, 256, 0, stream>>>(vT, cS, sevP, cevP, featT,
                                  wT + (size_t)t * NG * 64, ctxP);
        kF1<<<16, 256, 0, stream>>>(gihxAll + (size_t)t * 4 * NU * 64, ghh, ctxP, Wih,
                                    bih, bhh, cT_, hTall + (size_t)t * NU * 64,
                                    lnPS + (size_t)t * 1024, lnPQ + (size_t)t * 1024);
    }

    kS<<<120, 256, 0, stream>>>(hTall, lnPS, lnPQ, ln_g, ln_b, sTall);
    kHead1<<<240, 256, 0, stream>>>(sTall, W1, b1, h1All);
    kLogits<<<4688, 256, 0, stream>>>(h1All, W2, b2, lgAll, zPart);
    kZc<<<60, 256, 0, stream>>>(zPart, zQ);
    kOut<<<NT * 79, 256, 0, stream>>>(lgAll, zQ, out);
    kScoresT<<<NT * 6, 256, 0, stream>>>(wT, out);
}

// Round 5
// 1903.525 us; speedup vs baseline: 5.8059x; 1.0069x over previous
//
#include <hip/hip_runtime.h>
#include <math.h>

#define NG 360
#define NV 100
#define ND 32
#define NU 512
#define NT 15
#define NVOC 5000
#define NH 8
#define NE 544
#define NHD 68
#define OFF_SCORES 4800000
#define INV_SQRT_HD 0.12126781f
#define CS_SCALE 43.65636f

__device__ __forceinline__ float leaky(float x) { return x >= 0.f ? x : 0.2f * x; }
__device__ __forceinline__ float sigm(float x) { return 1.f / (1.f + expf(-x)); }
__device__ __forceinline__ unsigned short f2bf(float x) {
    unsigned b = __float_as_uint(x);
    return (unsigned short)((b + 0x7FFFu + ((b >> 16) & 1u)) >> 16);
}
__device__ __forceinline__ float lo16(unsigned p) { return __uint_as_float(p << 16); }
__device__ __forceinline__ float hi16(unsigned p) { return __uint_as_float(p & 0xffff0000u); }

// ---------- Weight packing: rows 2g,2g+1 -> one uint (bf16 lo/hi) ----------
__global__ __launch_bounds__(256) void kPack(const float* __restrict__ W, int ldw, int col0,
                                             int K, int total, unsigned* __restrict__ outp) {
    int idx = (int)blockIdx.x * 256 + (int)threadIdx.x;
    if (idx >= total) return;
    int g = idx / K, k = idx - g * K;          // K is a power of two
    float w0 = W[(size_t)(2 * g) * ldw + col0 + k];
    float w1 = W[(size_t)(2 * g + 1) * ldw + col0 + k];
    outp[idx] = (unsigned)f2bf(w0) | ((unsigned)f2bf(w1) << 16);
}

// ---------- Precompute ----------

__global__ void k_transpose_feat(const float* __restrict__ features, float* __restrict__ fX) {
    __shared__ float tile[64 * 65];
    int c0 = (int)blockIdx.x * 64;
    int tl = (int)threadIdx.x;
    int c = tl & 63, q0 = tl >> 6;
    for (int i = 0; i < 16; ++i) {
        int b = q0 + (i << 2);
        int col = c0 + c;
        float v = (col < NG * NV) ? features[b * (NG * NV) + col] : 0.f;
        tile[c * 65 + b] = v;
    }
    __syncthreads();
    int b2 = tl & 63, cr = tl >> 6;
    for (int i = 0; i < 16; ++i) {
        int c2 = cr + (i << 2);
        int col = c0 + c2;
        if (col < NG * NV) fX[col * 64 + b2] = tile[c2 * 65 + b2];
    }
}

__global__ __launch_bounds__(256) void k_encoder2(
        const float* __restrict__ fX, const float* __restrict__ enc_W,
        const float* __restrict__ enc_b, const float* __restrict__ enc_g,
        const float* __restrict__ enc_beta, float* __restrict__ featT) {
    __shared__ float fxs[6400];
    __shared__ float ps[256], pq[256];
    int g = (int)blockIdx.x, tid = (int)threadIdx.x;
    #pragma unroll
    for (int k = 0; k < 25; ++k) fxs[tid + k * 256] = fX[g * 6400 + tid + k * 256];
    __syncthreads();
    int lane = tid & 63, w = tid >> 6, d0 = w * 8;
    float acc[8];
    #pragma unroll
    for (int j = 0; j < 8; ++j) acc[j] = enc_b[g * 32 + d0 + j];
    const float* wb = enc_W + g * 3200 + d0 * 100;
    #pragma unroll 4
    for (int v = 0; v < 100; ++v) {
        float fv = fxs[v * 64 + lane];
        #pragma unroll
        for (int j = 0; j < 8; ++j) acc[j] += fv * wb[j * 100 + v];
    }
    float sm = 0.f, sq = 0.f;
    #pragma unroll
    for (int j = 0; j < 8; ++j) { sm += acc[j]; sq += acc[j] * acc[j]; }
    ps[tid] = sm; pq[tid] = sq;
    __syncthreads();
    float m = (ps[lane] + ps[64 + lane] + ps[128 + lane] + ps[192 + lane]) * (1.f / 32.f);
    float q = (pq[lane] + pq[64 + lane] + pq[128 + lane] + pq[192 + lane]);
    float var = q * (1.f / 32.f) - m * m;
    float rstd = 1.f / sqrtf(var + 1e-5f);
    #pragma unroll
    for (int j = 0; j < 8; ++j) {
        int d = d0 + j;
        float x = (acc[j] - m) * rstd * enc_g[d] + enc_beta[d];
        featT[(g * 32 + d) * 64 + lane] = leaky(x);
    }
}

__global__ void k_init_state(const float* __restrict__ a0, const float* __restrict__ c0,
                             float* __restrict__ aT0, float* __restrict__ cT) {
    __shared__ float tile[64 * 65];
    int which = (int)blockIdx.x >> 3;
    int t0 = ((int)blockIdx.x & 7) * 64;
    const float* src = which ? c0 : a0;
    int tl = (int)threadIdx.x;
    int c = tl & 63, q0 = tl >> 6;
    for (int i = 0; i < 16; ++i) {
        int b = q0 + (i << 2);
        tile[c * 65 + b] = src[b * NU + t0 + c];
    }
    __syncthreads();
    int b2 = tl & 63, cr = tl >> 6;
    for (int i = 0; i < 16; ++i) {
        int c2 = cr + (i << 2);
        float v = tile[c2 * 65 + b2];
        int idx = (t0 + c2) * 64 + b2;
        if (which) cT[idx] = v;
        else aT0[idx] = v;
    }
}

__global__ void k_embed(const int* __restrict__ text, const float* __restrict__ emb,
                        float* __restrict__ xT) {
    int t = (int)blockIdx.x;
    int tl = (int)threadIdx.x;
    int b = tl & 63, uq = tl >> 6;
    int row = text[b * NT + t];
    const float* er = emb + (long)row * NU;
    float* dst = xT + t * NU * 64;
    for (int i = 0; i < 128; ++i) {
        int u = uq + (i << 2);
        dst[u * 64 + b] = er[u];
    }
}

// kf2[(j*272 + e/2)][b] packs kf rows e,e+1 as bf16 pair
__global__ void k_kf(const float* __restrict__ featT, const float* __restrict__ in_w,
                     unsigned* __restrict__ kf2) {
    int wid = __builtin_amdgcn_readfirstlane((int)blockIdx.x * 4 + ((int)threadIdx.x >> 6));
    int lane = (int)threadIdx.x & 63;
    int j = wid / 34, et = wid % 34;
    if (j >= NG) return;
    int e0 = et * 16;
    float acc[16];
    #pragma unroll
    for (int jj = 0; jj < 16; ++jj) acc[jj] = 0.f;
    const float* ft = featT + j * ND * 64 + lane;
    const float* wr0 = in_w + (NE + e0) * NE;
    #pragma unroll 4
    for (int d = 0; d < ND; ++d) {
        float fv = ft[d * 64];
        #pragma unroll
        for (int jj = 0; jj < 16; ++jj) acc[jj] += fv * wr0[jj * NE + d];
    }
    unsigned* dst = kf2 + ((size_t)j * 272 + (e0 >> 1)) * 64 + lane;
    #pragma unroll
    for (int i = 0; i < 8; ++i)
        dst[i * 64] = (unsigned)f2bf(acc[2 * i]) | ((unsigned)f2bf(acc[2 * i + 1]) << 16);
}

__global__ void k_featmean(const float* __restrict__ featT, float* __restrict__ fmean) {
    int wid = __builtin_amdgcn_readfirstlane((int)blockIdx.x * 4 + ((int)threadIdx.x >> 6));
    int lane = (int)threadIdx.x & 63;
    if (wid >= ND) return;
    float s = 0.f;
    for (int g = 0; g < NG; ++g) s += featT[(g * ND + wid) * 64 + lane];
    fmean[wid * 64 + lane] = s * (1.f / 360.f);
}

__global__ void k_qmean(const float* __restrict__ fmean, const float* __restrict__ in_w,
                        float* __restrict__ qmean) {
    int wid = __builtin_amdgcn_readfirstlane((int)blockIdx.x * 4 + ((int)threadIdx.x >> 6));
    int lane = (int)threadIdx.x & 63;
    if (wid >= 68) return;
    int e0 = wid * 8;
    float acc[8];
    #pragma unroll
    for (int jj = 0; jj < 8; ++jj) acc[jj] = 0.f;
    #pragma unroll 4
    for (int d = 0; d < ND; ++d) {
        float fv = fmean[d * 64 + lane];
        #pragma unroll
        for (int jj = 0; jj < 8; ++jj) acc[jj] += fv * in_w[(e0 + jj) * NE + d];
    }
    #pragma unroll
    for (int jj = 0; jj < 8; ++jj) qmean[(e0 + jj) * 64 + lane] = acc[jj];
}

__global__ void k_cs(const float* __restrict__ qmean, const unsigned* __restrict__ kf2,
                     float* __restrict__ cS) {
    int wid = __builtin_amdgcn_readfirstlane((int)blockIdx.x * 4 + ((int)threadIdx.x >> 6));
    int lane = (int)threadIdx.x & 63;
    if (wid >= 720) return;
    int h = wid / 90, jt = wid % 90, j0 = jt * 4;
    float acc[4] = {0.f, 0.f, 0.f, 0.f};
    const float* qm = qmean + (h * NHD) * 64 + lane;
    const unsigned* kb = kf2 + ((size_t)j0 * 272 + h * 34) * 64 + lane;
    #pragma unroll 2
    for (int mp = 0; mp < 34; ++mp) {
        float q0 = qm[(2 * mp) * 64];
        float q1 = qm[(2 * mp + 1) * 64];
        #pragma unroll
        for (int j = 0; j < 4; ++j) {
            unsigned p = kb[((size_t)j * 272 + mp) * 64];
            acc[j] = fmaf(q0, lo16(p), acc[j]);
            acc[j] = fmaf(q1, hi16(p), acc[j]);
        }
    }
    #pragma unroll
    for (int jj = 0; jj < 4; ++jj) cS[(h * NG + j0 + jj) * 64 + lane] = acc[jj] * CS_SCALE;
}

// gihxAll via packed Wx (2-row groups): 15360 waves
__global__ __launch_bounds__(256) void k_gihx(const float* __restrict__ xT,
                                              const unsigned* __restrict__ Wxp,
                                              float* __restrict__ gihxAll) {
    int wid = __builtin_amdgcn_readfirstlane((int)blockIdx.x * 4 + ((int)threadIdx.x >> 6));
    int lane = (int)threadIdx.x & 63;
    int t = wid >> 10, g = wid & 1023, n0 = g * 2;
    const float* xb = xT + t * NU * 64;
    const unsigned* wb = Wxp + (size_t)g * 512;
    float acc0 = 0.f, acc1 = 0.f;
    #pragma unroll 4
    for (int k = 0; k < NU; ++k) {
        float xv = xb[k * 64 + lane];
        unsigned p = wb[k];
        acc0 = fmaf(lo16(p), xv, acc0);
        acc1 = fmaf(hi16(p), xv, acc1);
    }
    float* dst = gihxAll + (size_t)t * (4 * NU * 64) + n0 * 64 + lane;
    dst[0] = acc0;
    dst[64] = acc1;
}

// ---------- Per-step ----------

// 324 blocks (1296 waves): wid<272 qa 2-row groups, else ghh 2-row groups. LN folded.
__global__ __launch_bounds__(256) void kA(
        const float* __restrict__ aT0, const float* __restrict__ hTall,
        const float* __restrict__ lnPS, const float* __restrict__ lnPQ,
        const float* __restrict__ ln_g, const float* __restrict__ ln_b,
        const unsigned* __restrict__ Wqp, const float* __restrict__ in_b,
        const unsigned* __restrict__ Whhp,
        float* __restrict__ qaT, float* __restrict__ ghh, int t) {
    int wid = __builtin_amdgcn_readfirstlane((int)blockIdx.x * 4 + ((int)threadIdx.x >> 6));
    int lane = (int)threadIdx.x & 63;
    float rstd = 1.f, mneg = 0.f;
    const float* src = aT0;
    if (t > 0) {
        const float* pS = lnPS + (size_t)(t - 1) * 1024;
        const float* pQ = lnPQ + (size_t)(t - 1) * 1024;
        float ms = 0.f, qs = 0.f;
        #pragma unroll
        for (int i = 0; i < 16; ++i) { ms += pS[i * 64 + lane]; qs += pQ[i * 64 + lane]; }
        float m = ms * (1.f / 512.f);
        float var = qs * (1.f / 512.f) - m * m;
        rstd = 1.f / sqrtf(var + 1e-5f);
        mneg = -m * rstd;
        src = hTall + (size_t)(t - 1) * (NU * 64);
    }
    float acc0 = 0.f, acc1 = 0.f;
    const unsigned* wb;
    int n0;
    bool isQ = wid < 272;
    if (isQ) { n0 = wid * 2; wb = Wqp + (size_t)wid * 512; }
    else { n0 = (wid - 272) * 2; wb = Whhp + (size_t)(wid - 272) * 512; }
    if (t == 0) {
        #pragma unroll 4
        for (int k = 0; k < NU; ++k) {
            float av = src[k * 64 + lane];
            unsigned p = wb[k];
            acc0 = fmaf(lo16(p), av, acc0);
            acc1 = fmaf(hi16(p), av, acc1);
        }
    } else {
        #pragma unroll 4
        for (int k = 0; k < NU; ++k) {
            float hv = src[k * 64 + lane];
            float av = fmaf(fmaf(hv, rstd, mneg), ln_g[k], ln_b[k]);
            unsigned p = wb[k];
            acc0 = fmaf(lo16(p), av, acc0);
            acc1 = fmaf(hi16(p), av, acc1);
        }
    }
    if (isQ) {
        qaT[n0 * 64 + lane] = acc0 + in_b[n0];
        qaT[(n0 + 1) * 64 + lane] = acc1 + in_b[n0 + 1];
    } else {
        ghh[n0 * 64 + lane] = acc0;
        ghh[(n0 + 1) * 64 + lane] = acc1;
    }
}

// 180 blocks: v + exp partials (paired-d kf2 loads)
__global__ __launch_bounds__(256) void kB(
        const float* __restrict__ qaT, const unsigned* __restrict__ kf2,
        const float* __restrict__ cS,
        float* __restrict__ vT, float* __restrict__ sevP, float* __restrict__ cevP) {
    int wid = __builtin_amdgcn_readfirstlane((int)blockIdx.x * 4 + ((int)threadIdx.x >> 6));
    int lane = (int)threadIdx.x & 63;
    int h = wid / 90, jt = wid % 90, j0 = jt * 4;
    float acc[4] = {0.f, 0.f, 0.f, 0.f};
    const float* qm = qaT + (h * NHD) * 64 + lane;
    const unsigned* kb = kf2 + ((size_t)j0 * 272 + h * 34) * 64 + lane;
    #pragma unroll 2
    for (int mp = 0; mp < 34; ++mp) {
        float q0 = qm[(2 * mp) * 64];
        float q1 = qm[(2 * mp + 1) * 64];
        #pragma unroll
        for (int j = 0; j < 4; ++j) {
            unsigned p = kb[((size_t)j * 272 + mp) * 64];
            acc[j] = fmaf(q0, lo16(p), acc[j]);
            acc[j] = fmaf(q1, hi16(p), acc[j]);
        }
    }
    float eS = 0.f, eC = 0.f;
    #pragma unroll
    for (int j = 0; j < 4; ++j) {
        float v = acc[j] * INV_SQRT_HD;
        vT[(h * NG + j0 + j) * 64 + lane] = v;
        float e = expf(v);
        float c = cS[(h * NG + j0 + j) * 64 + lane];
        eS += e; eC += c * e;
    }
    sevP[wid * 64 + lane] = eS;
    cevP[wid * 64 + lane] = eC;
}

// 8 blocks: combine partials, W + wT write + ctx partials.
__global__ __launch_bounds__(256) void kC(
        const float* __restrict__ vT, const float* __restrict__ cS,
        const float* __restrict__ sevP, const float* __restrict__ cevP,
        const float* __restrict__ featT,
        float* __restrict__ wDst, float* __restrict__ ctxP) {
    __shared__ float SevL[512], CevL[512], Wl[45 * 64];
    int tid = (int)threadIdx.x, s = (int)blockIdx.x;
    int lane = tid & 63, w = tid >> 6;
    for (int hh = w; hh < 8; hh += 4) {
        float a = 0.f, c = 0.f;
        #pragma unroll 6
        for (int jt = 0; jt < 90; ++jt) {
            a += sevP[(hh * 90 + jt) * 64 + lane];
            c += cevP[(hh * 90 + jt) * 64 + lane];
        }
        SevL[hh * 64 + lane] = a;
        CevL[hh * 64 + lane] = c;
    }
    __syncthreads();
    float invS[8], cevM[8];
    #pragma unroll
    for (int hh = 0; hh < 8; ++hh) {
        float iv = 1.f / SevL[hh * 64 + lane];
        invS[hh] = iv;
        cevM[hh] = CevL[hh * 64 + lane] * iv;
    }
    int j0 = s * 45;
    for (int jj = w; jj < 45; jj += 4) {
        int j = j0 + jj;
        float acc = 0.f;
        #pragma unroll
        for (int hh = 0; hh < 8; ++hh) {
            float v = vT[(hh * NG + j) * 64 + lane];
            float e = expf(v);
            float c = cS[(hh * NG + j) * 64 + lane];
            acc += e * invS[hh] * (1.f + (c - cevM[hh]) * (1.f / 360.f));
        }
        float W = acc * 0.125f;
        Wl[jj * 64 + lane] = W;
        wDst[j * 64 + lane] = W;
    }
    __syncthreads();
    int d0 = w * 8;
    float acc[8];
    #pragma unroll
    for (int dd = 0; dd < 8; ++dd) acc[dd] = 0.f;
    for (int jj = 0; jj < 45; ++jj) {
        float wvv = Wl[jj * 64 + lane];
        const float* fb = featT + ((size_t)(j0 + jj) * ND + d0) * 64 + lane;
        #pragma unroll
        for (int dd = 0; dd < 8; ++dd) acc[dd] += wvv * fb[dd * 64];
    }
    #pragma unroll
    for (int dd = 0; dd < 8; ++dd) ctxP[s * 2048 + (d0 + dd) * 64 + lane] = acc[dd];
}

// 16 blocks (32 u each): gates + cell + h + LN partials.
__global__ __launch_bounds__(256) void kF1(
        const float* __restrict__ gihxT, const float* __restrict__ ghh,
        const float* __restrict__ ctxP, const float* __restrict__ Wih,
        const float* __restrict__ bih, const float* __restrict__ bhh,
        float* __restrict__ cT, float* __restrict__ hDst,
        float* __restrict__ lnPS, float* __restrict__ lnPQ) {
    __shared__ float ctxL[2048];
    __shared__ float rS[256], rQ[256];
    int tid = (int)threadIdx.x, bid = (int)blockIdx.x;
    #pragma unroll
    for (int k = 0; k < 8; ++k) {
        int idx = tid + k * 256;
        float s = 0.f;
        #pragma unroll
        for (int sl = 0; sl < 8; ++sl) s += ctxP[sl * 2048 + idx];
        ctxL[idx] = s;
    }
    __syncthreads();
    int lane = tid & 63, w = tid >> 6;
    float cx[32];
    #pragma unroll 8
    for (int d = 0; d < 32; ++d) cx[d] = ctxL[d * 64 + lane];
    int u0 = bid * 32 + w * 8;
    float ssum = 0.f, qsum = 0.f;
    for (int i = 0; i < 8; ++i) {
        int u = u0 + i;
        float g4[4];
        #pragma unroll
        for (int q = 0; q < 4; ++q) {
            int n = q * NU + u;
            float gv = gihxT[n * 64 + lane] + ghh[n * 64 + lane] + bih[n] + bhh[n];
            const float* wr = Wih + n * NE;
            #pragma unroll
            for (int d = 0; d < 32; ++d) gv += cx[d] * wr[d];
            g4[q] = gv;
        }
        float ig = sigm(g4[0]), fg = sigm(g4[1]), gg = tanhf(g4[2]), og = sigm(g4[3]);
        float cn = fg * cT[u * 64 + lane] + ig * gg;
        cT[u * 64 + lane] = cn;
        float hv = og * tanhf(cn);
        hDst[u * 64 + lane] = hv;
        ssum += hv; qsum += hv * hv;
    }
    rS[tid] = ssum; rQ[tid] = qsum;
    __syncthreads();
    if (tid < 64) {
        lnPS[bid * 64 + tid] = rS[tid] + rS[64 + tid] + rS[128 + tid] + rS[192 + tid];
        lnPQ[bid * 64 + tid] = rQ[tid] + rQ[64 + tid] + rQ[128 + tid] + rQ[192 + tid];
    }
}

// ---------- Post-loop head ----------

__global__ __launch_bounds__(256) void kS(const float* __restrict__ hTall,
                                          const float* __restrict__ lnPS, const float* __restrict__ lnPQ,
                                          const float* __restrict__ ln_g, const float* __restrict__ ln_b,
                                          float* __restrict__ sTall) {
    int bid = (int)blockIdx.x, tid = (int)threadIdx.x;
    int t = bid >> 3, sl = bid & 7;
    int lane = tid & 63, w = tid >> 6;
    const float* pS = lnPS + (size_t)t * 1024;
    const float* pQ = lnPQ + (size_t)t * 1024;
    float ms = 0.f, qs = 0.f;
    #pragma unroll
    for (int i = 0; i < 16; ++i) { ms += pS[i * 64 + lane]; qs += pQ[i * 64 + lane]; }
    float m = ms * (1.f / 512.f);
    float var = qs * (1.f / 512.f) - m * m;
    float rstd = 1.f / sqrtf(var + 1e-5f);
    for (int i = 0; i < 16; ++i) {
        int k = sl * 64 + w * 16 + i;
        float hv = hTall[((size_t)t * NU + k) * 64 + lane];
        float av = fmaf((hv - m) * rstd, ln_g[k], ln_b[k]);
        sTall[((size_t)t * NU + k) * 64 + lane] = leaky(av);
    }
}

// 480 blocks (1920 waves): h1 via packed W1
__global__ __launch_bounds__(256) void kHead1(const float* __restrict__ sTall,
                                              const unsigned* __restrict__ W1p, const float* __restrict__ b1,
                                              float* __restrict__ h1All) {
    int wid = __builtin_amdgcn_readfirstlane((int)blockIdx.x * 4 + ((int)threadIdx.x >> 6));
    int lane = (int)threadIdx.x & 63;
    int t = wid >> 7, g = wid & 127, n0 = g * 2;
    const float* sb = sTall + (size_t)t * NU * 64;
    const unsigned* wb = W1p + (size_t)g * 512;
    float acc0 = 0.f, acc1 = 0.f;
    #pragma unroll 4
    for (int k = 0; k < NU; ++k) {
        float sv = sb[k * 64 + lane];
        unsigned p = wb[k];
        acc0 = fmaf(lo16(p), sv, acc0);
        acc1 = fmaf(hi16(p), sv, acc1);
    }
    float* dst = h1All + ((size_t)t * 256 + n0) * 64 + lane;
    dst[0] = leaky(acc0 + b1[n0]);
    dst[64] = leaky(acc1 + b1[n0 + 1]);
}

// 9375 blocks (37500 waves): logits via packed W2 + exp partials
__global__ __launch_bounds__(256) void kLogits(const float* __restrict__ h1All,
                                               const unsigned* __restrict__ W2p, const float* __restrict__ b2,
                                               float* __restrict__ lgAll, float* __restrict__ zPart) {
    int wid = __builtin_amdgcn_readfirstlane((int)blockIdx.x * 4 + ((int)threadIdx.x >> 6));
    int lane = (int)threadIdx.x & 63;
    int t = wid / 2500, g = wid % 2500, n0 = g * 2;
    const float* hb = h1All + (size_t)t * 256 * 64;
    const unsigned* wb = W2p + (size_t)g * 256;
    float acc0 = 0.f, acc1 = 0.f;
    #pragma unroll 4
    for (int k = 0; k < 256; ++k) {
        float hv = hb[k * 64 + lane];
        unsigned p = wb[k];
        acc0 = fmaf(lo16(p), hv, acc0);
        acc1 = fmaf(hi16(p), hv, acc1);
    }
    float lg0 = acc0 + b2[n0];
    float lg1 = acc1 + b2[n0 + 1];
    float* dst = lgAll + ((size_t)t * NVOC + n0) * 64 + lane;
    dst[0] = lg0;
    dst[64] = lg1;
    zPart[(size_t)wid * 64 + lane] = expf(lg0) + expf(lg1);
}

// 60 blocks: combine exp partials (pure loads)
__global__ __launch_bounds__(256) void kZc(const float* __restrict__ zPart, float* __restrict__ zQ) {
    __shared__ float red[256];
    int bid = (int)blockIdx.x, tid = (int)threadIdx.x;
    int t = bid >> 2, qd = bid & 3;
    int lane = tid & 63, w = tid >> 6;
    float p = 0.f;
    for (int i = w; i < 625; i += 4)
        p += zPart[((size_t)t * 2500 + qd * 625 + i) * 64 + lane];
    red[tid] = p;
    __syncthreads();
    if (tid < 64) zQ[bid * 64 + tid] = red[tid] + red[64 + tid] + red[128 + tid] + red[192 + tid];
}

__global__ __launch_bounds__(256) void kOut(const float* __restrict__ lgAll,
                                            const float* __restrict__ zQ, float* __restrict__ out) {
    __shared__ float tile[64 * 65];
    int bid = (int)blockIdx.x;
    int t = bid / 79, nt = bid % 79;
    int n0 = nt * 64;
    int tid = (int)threadIdx.x, lane = tid & 63, w = tid >> 6;
    const float* lg = lgAll + (size_t)t * (NVOC * 64);
    float z = zQ[(t * 4) * 64 + lane] + zQ[(t * 4 + 1) * 64 + lane] +
              zQ[(t * 4 + 2) * 64 + lane] + zQ[(t * 4 + 3) * 64 + lane];
    float invZ = 1.f / z;
    for (int i = 0; i < 16; ++i) {
        int r = w * 16 + i, n = n0 + r;
        if (n < NVOC) tile[r * 65 + lane] = expf(lg[n * 64 + lane]) * invZ;
    }
    __syncthreads();
    for (int i = 0; i < 16; ++i) {
        int b = w * 16 + i;
        int n = n0 + lane;
        if (n < NVOC) out[(size_t)b * (NT * NVOC) + t * NVOC + n] = tile[lane * 65 + b];
    }
}

__global__ __launch_bounds__(256) void kScoresT(const float* __restrict__ wT, float* __restrict__ out) {
    __shared__ float tile[64 * 65];
    int bid = (int)blockIdx.x;
    int t = bid / 6, jt = bid % 6;
    int j0 = jt * 64;
    int tid = (int)threadIdx.x, lane = tid & 63, w = tid >> 6;
    for (int i = 0; i < 16; ++i) {
        int r = w * 16 + i, j = j0 + r;
        if (j < NG) tile[r * 65 + lane] = wT[(size_t)t * (NG * 64) + j * 64 + lane];
    }
    __syncthreads();
    for (int i = 0; i < 16; ++i) {
        int b = w * 16 + i;
        int j = j0 + lane;
        if (j < NG) out[OFF_SCORES + (size_t)b * (NT * NG) + t * NG + j] = tile[lane * 65 + b];
    }
}

// ---------- Launch ----------
extern "C" void kernel_launch(void* const* d_in, const int* in_sizes, int n_in,
                              void* d_out, int out_size, void* d_ws, size_t ws_size,
                              hipStream_t stream) {
    const float* features = (const float*)d_in[0];
    const int*   text     = (const int*)d_in[1];
    const float* a0       = (const float*)d_in[2];
    const float* c0       = (const float*)d_in[3];
    const float* enc_W    = (const float*)d_in[4];
    const float* enc_b    = (const float*)d_in[5];
    const float* enc_g    = (const float*)d_in[6];
    const float* enc_beta = (const float*)d_in[7];
    const float* emb      = (const float*)d_in[8];
    const float* in_w     = (const float*)d_in[9];
    const float* in_b     = (const float*)d_in[10];
    const float* Wih      = (const float*)d_in[11];
    const float* Whh      = (const float*)d_in[12];
    const float* bih      = (const float*)d_in[13];
    const float* bhh      = (const float*)d_in[14];
    const float* ln_g     = (const float*)d_in[15];
    const float* ln_b     = (const float*)d_in[16];
    const float* W1       = (const float*)d_in[17];
    const float* b1       = (const float*)d_in[18];
    const float* W2       = (const float*)d_in[19];
    const float* b2       = (const float*)d_in[20];
    float* out = (float*)d_out;

    float* ws = (float*)d_ws;
    size_t off = 0;
    auto alloc = [&](size_t n) { float* p = ws + off; off += (n + 63) & ~(size_t)63; return p; };
    float* lgAll   = alloc((size_t)NT * NVOC * 64);   // aliased as fX pre-loop
    float* fX      = lgAll;
    float* featT   = alloc((size_t)NG * ND * 64);
    float* xT      = alloc((size_t)NT * NU * 64);
    float* gihxAll = alloc((size_t)NT * 4 * NU * 64);
    unsigned* kf2  = (unsigned*)alloc((size_t)NG * 272 * 64);
    float* wT      = alloc((size_t)NT * NG * 64);
    float* vT      = alloc((size_t)NH * NG * 64);
    float* cS      = alloc((size_t)NH * NG * 64);
    float* fmean   = alloc((size_t)ND * 64);
    float* qmean   = alloc((size_t)NE * 64);
    float* aT0     = alloc((size_t)NU * 64);
    float* cT_     = alloc((size_t)NU * 64);
    float* hTall   = alloc((size_t)NT * NU * 64);
    float* sTall   = alloc((size_t)NT * NU * 64);
    float* h1All   = alloc((size_t)NT * 256 * 64);
    float* qaT     = alloc((size_t)NE * 64);
    float* ghh     = alloc((size_t)4 * NU * 64);
    float* sevP    = alloc((size_t)720 * 64);
    float* cevP    = alloc((size_t)720 * 64);
    float* ctxP    = alloc((size_t)8 * ND * 64);
    float* lnPS    = alloc((size_t)NT * 16 * 64);
    float* lnPQ    = alloc((size_t)NT * 16 * 64);
    float* zPart   = alloc((size_t)NT * 2500 * 64);
    float* zQ      = alloc((size_t)NT * 4 * 64);
    unsigned* Wqp  = (unsigned*)alloc((size_t)272 * 512);
    unsigned* Whhp = (unsigned*)alloc((size_t)1024 * 512);
    unsigned* Wxp  = (unsigned*)alloc((size_t)1024 * 512);
    unsigned* W1p  = (unsigned*)alloc((size_t)128 * 512);
    unsigned* W2p  = (unsigned*)alloc((size_t)2500 * 256);

    // weight packing (bf16 pairs)
    kPack<<<544, 256, 0, stream>>>(in_w, NE, ND, 512, 272 * 512, Wqp);
    kPack<<<2048, 256, 0, stream>>>(Whh, NU, 0, 512, 1024 * 512, Whhp);
    kPack<<<2048, 256, 0, stream>>>(Wih, NE, ND, 512, 1024 * 512, Wxp);
    kPack<<<256, 256, 0, stream>>>(W1, NU, 0, 512, 128 * 512, W1p);
    kPack<<<2500, 256, 0, stream>>>(W2, 256, 0, 256, 2500 * 256, W2p);

    k_transpose_feat<<<563, 256, 0, stream>>>(features, fX);
    k_encoder2<<<NG, 256, 0, stream>>>(fX, enc_W, enc_b, enc_g, enc_beta, featT);
    k_init_state<<<16, 256, 0, stream>>>(a0, c0, aT0, cT_);
    k_embed<<<NT, 256, 0, stream>>>(text, emb, xT);
    k_kf<<<3060, 256, 0, stream>>>(featT, in_w, kf2);
    k_featmean<<<8, 256, 0, stream>>>(featT, fmean);
    k_qmean<<<17, 256, 0, stream>>>(fmean, in_w, qmean);
    k_cs<<<180, 256, 0, stream>>>(qmean, kf2, cS);
    k_gihx<<<3840, 256, 0, stream>>>(xT, Wxp, gihxAll);

    for (int t = 0; t < NT; ++t) {
        kA<<<324, 256, 0, stream>>>(aT0, hTall, lnPS, lnPQ, ln_g, ln_b,
                                    Wqp, in_b, Whhp, qaT, ghh, t);
        kB<<<180, 256, 0, stream>>>(qaT, kf2, cS, vT, sevP, cevP);
        kC<<<8, 256, 0, stream>>>(vT, cS, sevP, cevP, featT,
                                  wT + (size_t)t * NG * 64, ctxP);
        kF1<<<16, 256, 0, stream>>>(gihxAll + (size_t)t * 4 * NU * 64, ghh, ctxP, Wih,
                                    bih, bhh, cT_, hTall + (size_t)t * NU * 64,
                                    lnPS + (size_t)t * 1024, lnPQ + (size_t)t * 1024);
    }

    kS<<<120, 256, 0, stream>>>(hTall, lnPS, lnPQ, ln_g, ln_b, sTall);
    kHead1<<<480, 256, 0, stream>>>(sTall, W1p, b1, h1All);
    kLogits<<<9375, 256, 0, stream>>>(h1All, W2p, b2, lgAll, zPart);
    kZc<<<60, 256, 0, stream>>>(zPart, zQ);
    kOut<<<NT * 79, 256, 0, stream>>>(lgAll, zQ, out);
    kScoresT<<<NT * 6, 256, 0, stream>>>(wT, out);
}

// Round 6
// 1762.010 us; speedup vs baseline: 6.2722x; 1.0803x over previous
//
#include <hip/hip_runtime.h>
#include <math.h>

#define NG 360
#define NV 100
#define ND 32
#define NU 512
#define NT 15
#define NVOC 5000
#define NH 8
#define NE 544
#define NHD 68
#define OFF_SCORES 4800000
#define INV_SQRT_HD 0.12126781f
#define CS_SCALE 43.65636f

typedef short bf16x8 __attribute__((ext_vector_type(8)));
typedef float f32x4 __attribute__((ext_vector_type(4)));

__device__ __forceinline__ float leaky(float x) { return x >= 0.f ? x : 0.2f * x; }
__device__ __forceinline__ float sigm(float x) { return 1.f / (1.f + expf(-x)); }
__device__ __forceinline__ unsigned short f2bf(float x) {
    unsigned b = __float_as_uint(x);
    return (unsigned short)((b + 0x7FFFu + ((b >> 16) & 1u)) >> 16);
}
__device__ __forceinline__ float lo16(unsigned p) { return __uint_as_float(p << 16); }
__device__ __forceinline__ float hi16(unsigned p) { return __uint_as_float(p & 0xffff0000u); }

// ---------- Weight packing: rows 2g,2g+1 -> one uint (bf16 lo/hi) ----------
__global__ __launch_bounds__(256) void kPack(const float* __restrict__ W, int ldw, int col0,
                                             int K, int total, unsigned* __restrict__ outp) {
    int idx = (int)blockIdx.x * 256 + (int)threadIdx.x;
    if (idx >= total) return;
    int g = idx / K, k = idx - g * K;
    float w0 = W[(size_t)(2 * g) * ldw + col0 + k];
    float w1 = W[(size_t)(2 * g + 1) * ldw + col0 + k];
    outp[idx] = (unsigned)f2bf(w0) | ((unsigned)f2bf(w1) << 16);
}

// W2 -> plain bf16 row-major [5008][256] (8 pad rows zeroed)
__global__ __launch_bounds__(256) void kCvtW2(const float* __restrict__ W2,
                                              unsigned short* __restrict__ W2bf) {
    int idx = (int)blockIdx.x * 256 + (int)threadIdx.x;
    if (idx < NVOC * 256) W2bf[idx] = f2bf(W2[idx]);
    else if (idx < 5008 * 256) W2bf[idx] = 0;
}

// ---------- Precompute ----------

__global__ void k_transpose_feat(const float* __restrict__ features, float* __restrict__ fX) {
    __shared__ float tile[64 * 65];
    int c0 = (int)blockIdx.x * 64;
    int tl = (int)threadIdx.x;
    int c = tl & 63, q0 = tl >> 6;
    for (int i = 0; i < 16; ++i) {
        int b = q0 + (i << 2);
        int col = c0 + c;
        float v = (col < NG * NV) ? features[b * (NG * NV) + col] : 0.f;
        tile[c * 65 + b] = v;
    }
    __syncthreads();
    int b2 = tl & 63, cr = tl >> 6;
    for (int i = 0; i < 16; ++i) {
        int c2 = cr + (i << 2);
        int col = c0 + c2;
        if (col < NG * NV) fX[col * 64 + b2] = tile[c2 * 65 + b2];
    }
}

__global__ __launch_bounds__(256) void k_encoder2(
        const float* __restrict__ fX, const float* __restrict__ enc_W,
        const float* __restrict__ enc_b, const float* __restrict__ enc_g,
        const float* __restrict__ enc_beta, float* __restrict__ featT) {
    __shared__ float fxs[6400];
    __shared__ float ps[256], pq[256];
    int g = (int)blockIdx.x, tid = (int)threadIdx.x;
    #pragma unroll
    for (int k = 0; k < 25; ++k) fxs[tid + k * 256] = fX[g * 6400 + tid + k * 256];
    __syncthreads();
    int lane = tid & 63, w = tid >> 6, d0 = w * 8;
    float acc[8];
    #pragma unroll
    for (int j = 0; j < 8; ++j) acc[j] = enc_b[g * 32 + d0 + j];
    const float* wb = enc_W + g * 3200 + d0 * 100;
    #pragma unroll 4
    for (int v = 0; v < 100; ++v) {
        float fv = fxs[v * 64 + lane];
        #pragma unroll
        for (int j = 0; j < 8; ++j) acc[j] += fv * wb[j * 100 + v];
    }
    float sm = 0.f, sq = 0.f;
    #pragma unroll
    for (int j = 0; j < 8; ++j) { sm += acc[j]; sq += acc[j] * acc[j]; }
    ps[tid] = sm; pq[tid] = sq;
    __syncthreads();
    float m = (ps[lane] + ps[64 + lane] + ps[128 + lane] + ps[192 + lane]) * (1.f / 32.f);
    float q = (pq[lane] + pq[64 + lane] + pq[128 + lane] + pq[192 + lane]);
    float var = q * (1.f / 32.f) - m * m;
    float rstd = 1.f / sqrtf(var + 1e-5f);
    #pragma unroll
    for (int j = 0; j < 8; ++j) {
        int d = d0 + j;
        float x = (acc[j] - m) * rstd * enc_g[d] + enc_beta[d];
        featT[(g * 32 + d) * 64 + lane] = leaky(x);
    }
}

__global__ void k_init_state(const float* __restrict__ a0, const float* __restrict__ c0,
                             float* __restrict__ aT0, float* __restrict__ cT) {
    __shared__ float tile[64 * 65];
    int which = (int)blockIdx.x >> 3;
    int t0 = ((int)blockIdx.x & 7) * 64;
    const float* src = which ? c0 : a0;
    int tl = (int)threadIdx.x;
    int c = tl & 63, q0 = tl >> 6;
    for (int i = 0; i < 16; ++i) {
        int b = q0 + (i << 2);
        tile[c * 65 + b] = src[b * NU + t0 + c];
    }
    __syncthreads();
    int b2 = tl & 63, cr = tl >> 6;
    for (int i = 0; i < 16; ++i) {
        int c2 = cr + (i << 2);
        float v = tile[c2 * 65 + b2];
        int idx = (t0 + c2) * 64 + b2;
        if (which) cT[idx] = v;
        else aT0[idx] = v;
    }
}

__global__ void k_embed(const int* __restrict__ text, const float* __restrict__ emb,
                        float* __restrict__ xT) {
    int t = (int)blockIdx.x;
    int tl = (int)threadIdx.x;
    int b = tl & 63, uq = tl >> 6;
    int row = text[b * NT + t];
    const float* er = emb + (long)row * NU;
    float* dst = xT + t * NU * 64;
    for (int i = 0; i < 128; ++i) {
        int u = uq + (i << 2);
        dst[u * 64 + b] = er[u];
    }
}

// kf2[(j*272 + e/2)][b] packs kf rows e,e+1 as bf16 pair
__global__ void k_kf(const float* __restrict__ featT, const float* __restrict__ in_w,
                     unsigned* __restrict__ kf2) {
    int wid = __builtin_amdgcn_readfirstlane((int)blockIdx.x * 4 + ((int)threadIdx.x >> 6));
    int lane = (int)threadIdx.x & 63;
    int j = wid / 34, et = wid % 34;
    if (j >= NG) return;
    int e0 = et * 16;
    float acc[16];
    #pragma unroll
    for (int jj = 0; jj < 16; ++jj) acc[jj] = 0.f;
    const float* ft = featT + j * ND * 64 + lane;
    const float* wr0 = in_w + (NE + e0) * NE;
    #pragma unroll 4
    for (int d = 0; d < ND; ++d) {
        float fv = ft[d * 64];
        #pragma unroll
        for (int jj = 0; jj < 16; ++jj) acc[jj] += fv * wr0[jj * NE + d];
    }
    unsigned* dst = kf2 + ((size_t)j * 272 + (e0 >> 1)) * 64 + lane;
    #pragma unroll
    for (int i = 0; i < 8; ++i)
        dst[i * 64] = (unsigned)f2bf(acc[2 * i]) | ((unsigned)f2bf(acc[2 * i + 1]) << 16);
}

__global__ void k_featmean(const float* __restrict__ featT, float* __restrict__ fmean) {
    int wid = __builtin_amdgcn_readfirstlane((int)blockIdx.x * 4 + ((int)threadIdx.x >> 6));
    int lane = (int)threadIdx.x & 63;
    if (wid >= ND) return;
    float s = 0.f;
    for (int g = 0; g < NG; ++g) s += featT[(g * ND + wid) * 64 + lane];
    fmean[wid * 64 + lane] = s * (1.f / 360.f);
}

__global__ void k_qmean(const float* __restrict__ fmean, const float* __restrict__ in_w,
                        float* __restrict__ qmean) {
    int wid = __builtin_amdgcn_readfirstlane((int)blockIdx.x * 4 + ((int)threadIdx.x >> 6));
    int lane = (int)threadIdx.x & 63;
    if (wid >= 68) return;
    int e0 = wid * 8;
    float acc[8];
    #pragma unroll
    for (int jj = 0; jj < 8; ++jj) acc[jj] = 0.f;
    #pragma unroll 4
    for (int d = 0; d < ND; ++d) {
        float fv = fmean[d * 64 + lane];
        #pragma unroll
        for (int jj = 0; jj < 8; ++jj) acc[jj] += fv * in_w[(e0 + jj) * NE + d];
    }
    #pragma unroll
    for (int jj = 0; jj < 8; ++jj) qmean[(e0 + jj) * 64 + lane] = acc[jj];
}

__global__ void k_cs(const float* __restrict__ qmean, const unsigned* __restrict__ kf2,
                     float* __restrict__ cS) {
    int wid = __builtin_amdgcn_readfirstlane((int)blockIdx.x * 4 + ((int)threadIdx.x >> 6));
    int lane = (int)threadIdx.x & 63;
    if (wid >= 720) return;
    int h = wid / 90, jt = wid % 90, j0 = jt * 4;
    float acc[4] = {0.f, 0.f, 0.f, 0.f};
    const float* qm = qmean + (h * NHD) * 64 + lane;
    const unsigned* kb = kf2 + ((size_t)j0 * 272 + h * 34) * 64 + lane;
    #pragma unroll 2
    for (int mp = 0; mp < 34; ++mp) {
        float q0 = qm[(2 * mp) * 64];
        float q1 = qm[(2 * mp + 1) * 64];
        #pragma unroll
        for (int j = 0; j < 4; ++j) {
            unsigned p = kb[((size_t)j * 272 + mp) * 64];
            acc[j] = fmaf(q0, lo16(p), acc[j]);
            acc[j] = fmaf(q1, hi16(p), acc[j]);
        }
    }
    #pragma unroll
    for (int jj = 0; jj < 4; ++jj) cS[(h * NG + j0 + jj) * 64 + lane] = acc[jj] * CS_SCALE;
}

// gihxAll: 4 rows/wave, 7680 waves
__global__ __launch_bounds__(256) void k_gihx(const float* __restrict__ xT,
                                              const unsigned* __restrict__ Wxp,
                                              float* __restrict__ gihxAll) {
    int wid = __builtin_amdgcn_readfirstlane((int)blockIdx.x * 4 + ((int)threadIdx.x >> 6));
    int lane = (int)threadIdx.x & 63;
    int t = wid >> 9, g = wid & 511, n0 = g * 4;
    const float* xb = xT + t * NU * 64;
    const unsigned* wb0 = Wxp + (size_t)(2 * g) * 512;
    const unsigned* wb1 = wb0 + 512;
    float a0 = 0.f, a1 = 0.f, a2 = 0.f, a3 = 0.f;
    #pragma unroll 4
    for (int k = 0; k < NU; ++k) {
        float xv = xb[k * 64 + lane];
        unsigned p0 = wb0[k], p1 = wb1[k];
        a0 = fmaf(lo16(p0), xv, a0);
        a1 = fmaf(hi16(p0), xv, a1);
        a2 = fmaf(lo16(p1), xv, a2);
        a3 = fmaf(hi16(p1), xv, a3);
    }
    float* dst = gihxAll + (size_t)t * (4 * NU * 64) + n0 * 64 + lane;
    dst[0] = a0; dst[64] = a1; dst[128] = a2; dst[192] = a3;
}

// ---------- Per-step ----------

// 162 blocks (648 waves): wid<136 qa (4 rows), else ghh (4 rows). LN folded.
__global__ __launch_bounds__(256) void kA(
        const float* __restrict__ aT0, const float* __restrict__ hTall,
        const float* __restrict__ lnPS, const float* __restrict__ lnPQ,
        const float* __restrict__ ln_g, const float* __restrict__ ln_b,
        const unsigned* __restrict__ Wqp, const float* __restrict__ in_b,
        const unsigned* __restrict__ Whhp,
        float* __restrict__ qaT, float* __restrict__ ghh, int t) {
    int wid = __builtin_amdgcn_readfirstlane((int)blockIdx.x * 4 + ((int)threadIdx.x >> 6));
    int lane = (int)threadIdx.x & 63;
    float rstd = 1.f, mneg = 0.f;
    const float* src = aT0;
    if (t > 0) {
        const float* pS = lnPS + (size_t)(t - 1) * 2048;
        const float* pQ = lnPQ + (size_t)(t - 1) * 2048;
        float ms = 0.f, qs = 0.f;
        #pragma unroll 8
        for (int i = 0; i < 32; ++i) { ms += pS[i * 64 + lane]; qs += pQ[i * 64 + lane]; }
        float m = ms * (1.f / 512.f);
        float var = qs * (1.f / 512.f) - m * m;
        rstd = 1.f / sqrtf(var + 1e-5f);
        mneg = -m * rstd;
        src = hTall + (size_t)(t - 1) * (NU * 64);
    }
    float a0 = 0.f, a1 = 0.f, a2 = 0.f, a3 = 0.f;
    const unsigned *wb0, *wb1;
    int n0;
    bool isQ = wid < 136;
    if (isQ) { n0 = wid * 4; wb0 = Wqp + (size_t)(2 * wid) * 512; }
    else { n0 = (wid - 136) * 4; wb0 = Whhp + (size_t)(2 * (wid - 136)) * 512; }
    wb1 = wb0 + 512;
    if (t == 0) {
        #pragma unroll 4
        for (int k = 0; k < NU; ++k) {
            float av = src[k * 64 + lane];
            unsigned p0 = wb0[k], p1 = wb1[k];
            a0 = fmaf(lo16(p0), av, a0);
            a1 = fmaf(hi16(p0), av, a1);
            a2 = fmaf(lo16(p1), av, a2);
            a3 = fmaf(hi16(p1), av, a3);
        }
    } else {
        #pragma unroll 4
        for (int k = 0; k < NU; ++k) {
            float hv = src[k * 64 + lane];
            float av = fmaf(fmaf(hv, rstd, mneg), ln_g[k], ln_b[k]);
            unsigned p0 = wb0[k], p1 = wb1[k];
            a0 = fmaf(lo16(p0), av, a0);
            a1 = fmaf(hi16(p0), av, a1);
            a2 = fmaf(lo16(p1), av, a2);
            a3 = fmaf(hi16(p1), av, a3);
        }
    }
    if (isQ) {
        qaT[n0 * 64 + lane] = a0 + in_b[n0];
        qaT[(n0 + 1) * 64 + lane] = a1 + in_b[n0 + 1];
        qaT[(n0 + 2) * 64 + lane] = a2 + in_b[n0 + 2];
        qaT[(n0 + 3) * 64 + lane] = a3 + in_b[n0 + 3];
    } else {
        ghh[n0 * 64 + lane] = a0;
        ghh[(n0 + 1) * 64 + lane] = a1;
        ghh[(n0 + 2) * 64 + lane] = a2;
        ghh[(n0 + 3) * 64 + lane] = a3;
    }
}

// 180 blocks: v + exp partials
__global__ __launch_bounds__(256) void kB(
        const float* __restrict__ qaT, const unsigned* __restrict__ kf2,
        const float* __restrict__ cS,
        float* __restrict__ vT, float* __restrict__ sevP, float* __restrict__ cevP) {
    int wid = __builtin_amdgcn_readfirstlane((int)blockIdx.x * 4 + ((int)threadIdx.x >> 6));
    int lane = (int)threadIdx.x & 63;
    int h = wid / 90, jt = wid % 90, j0 = jt * 4;
    float acc[4] = {0.f, 0.f, 0.f, 0.f};
    const float* qm = qaT + (h * NHD) * 64 + lane;
    const unsigned* kb = kf2 + ((size_t)j0 * 272 + h * 34) * 64 + lane;
    #pragma unroll 2
    for (int mp = 0; mp < 34; ++mp) {
        float q0 = qm[(2 * mp) * 64];
        float q1 = qm[(2 * mp + 1) * 64];
        #pragma unroll
        for (int j = 0; j < 4; ++j) {
            unsigned p = kb[((size_t)j * 272 + mp) * 64];
            acc[j] = fmaf(q0, lo16(p), acc[j]);
            acc[j] = fmaf(q1, hi16(p), acc[j]);
        }
    }
    float eS = 0.f, eC = 0.f;
    #pragma unroll
    for (int j = 0; j < 4; ++j) {
        float v = acc[j] * INV_SQRT_HD;
        vT[(h * NG + j0 + j) * 64 + lane] = v;
        float e = expf(v);
        float c = cS[(h * NG + j0 + j) * 64 + lane];
        eS += e; eC += c * e;
    }
    sevP[wid * 64 + lane] = eS;
    cevP[wid * 64 + lane] = eC;
}

// 24 blocks (15 j each): combine partials, W + wT write + ctx partials.
__global__ __launch_bounds__(256) void kC(
        const float* __restrict__ vT, const float* __restrict__ cS,
        const float* __restrict__ sevP, const float* __restrict__ cevP,
        const float* __restrict__ featT,
        float* __restrict__ wDst, float* __restrict__ ctxP) {
    __shared__ float SevL[512], CevL[512], Wl[15 * 64];
    int tid = (int)threadIdx.x, s = (int)blockIdx.x;
    int lane = tid & 63, w = tid >> 6;
    for (int hh = w; hh < 8; hh += 4) {
        float a = 0.f, c = 0.f;
        #pragma unroll 6
        for (int jt = 0; jt < 90; ++jt) {
            a += sevP[(hh * 90 + jt) * 64 + lane];
            c += cevP[(hh * 90 + jt) * 64 + lane];
        }
        SevL[hh * 64 + lane] = a;
        CevL[hh * 64 + lane] = c;
    }
    __syncthreads();
    float invS[8], cevM[8];
    #pragma unroll
    for (int hh = 0; hh < 8; ++hh) {
        float iv = 1.f / SevL[hh * 64 + lane];
        invS[hh] = iv;
        cevM[hh] = CevL[hh * 64 + lane] * iv;
    }
    int j0 = s * 15;
    for (int jj = w; jj < 15; jj += 4) {
        int j = j0 + jj;
        float acc = 0.f;
        #pragma unroll
        for (int hh = 0; hh < 8; ++hh) {
            float v = vT[(hh * NG + j) * 64 + lane];
            float e = expf(v);
            float c = cS[(hh * NG + j) * 64 + lane];
            acc += e * invS[hh] * (1.f + (c - cevM[hh]) * (1.f / 360.f));
        }
        float W = acc * 0.125f;
        Wl[jj * 64 + lane] = W;
        wDst[j * 64 + lane] = W;
    }
    __syncthreads();
    int d0 = w * 8;
    float acc[8];
    #pragma unroll
    for (int dd = 0; dd < 8; ++dd) acc[dd] = 0.f;
    for (int jj = 0; jj < 15; ++jj) {
        float wvv = Wl[jj * 64 + lane];
        const float* fb = featT + ((size_t)(j0 + jj) * ND + d0) * 64 + lane;
        #pragma unroll
        for (int dd = 0; dd < 8; ++dd) acc[dd] += wvv * fb[dd * 64];
    }
    #pragma unroll
    for (int dd = 0; dd < 8; ++dd) ctxP[s * 2048 + (d0 + dd) * 64 + lane] = acc[dd];
}

// 32 blocks (16 u each): gates + cell + h + LN partials.
__global__ __launch_bounds__(256) void kF1(
        const float* __restrict__ gihxT, const float* __restrict__ ghh,
        const float* __restrict__ ctxP, const float* __restrict__ Wih,
        const float* __restrict__ bih, const float* __restrict__ bhh,
        float* __restrict__ cT, float* __restrict__ hDst,
        float* __restrict__ lnPS, float* __restrict__ lnPQ) {
    __shared__ float ctxL[2048];
    __shared__ float rS[256], rQ[256];
    int tid = (int)threadIdx.x, bid = (int)blockIdx.x;
    #pragma unroll
    for (int k = 0; k < 8; ++k) {
        int idx = tid + k * 256;
        float s = 0.f;
        #pragma unroll 8
        for (int sl = 0; sl < 24; ++sl) s += ctxP[sl * 2048 + idx];
        ctxL[idx] = s;
    }
    __syncthreads();
    int lane = tid & 63, w = tid >> 6;
    float cx[32];
    #pragma unroll 8
    for (int d = 0; d < 32; ++d) cx[d] = ctxL[d * 64 + lane];
    int u0 = bid * 16 + w * 4;
    float ssum = 0.f, qsum = 0.f;
    for (int i = 0; i < 4; ++i) {
        int u = u0 + i;
        float g4[4];
        #pragma unroll
        for (int q = 0; q < 4; ++q) {
            int n = q * NU + u;
            float gv = gihxT[n * 64 + lane] + ghh[n * 64 + lane] + bih[n] + bhh[n];
            const float* wr = Wih + n * NE;
            #pragma unroll
            for (int d = 0; d < 32; ++d) gv += cx[d] * wr[d];
            g4[q] = gv;
        }
        float ig = sigm(g4[0]), fg = sigm(g4[1]), gg = tanhf(g4[2]), og = sigm(g4[3]);
        float cn = fg * cT[u * 64 + lane] + ig * gg;
        cT[u * 64 + lane] = cn;
        float hv = og * tanhf(cn);
        hDst[u * 64 + lane] = hv;
        ssum += hv; qsum += hv * hv;
    }
    rS[tid] = ssum; rQ[tid] = qsum;
    __syncthreads();
    if (tid < 64) {
        lnPS[bid * 64 + tid] = rS[tid] + rS[64 + tid] + rS[128 + tid] + rS[192 + tid];
        lnPQ[bid * 64 + tid] = rQ[tid] + rQ[64 + tid] + rQ[128 + tid] + rQ[192 + tid];
    }
}

// ---------- Post-loop head ----------

// 480 blocks (1920 waves): h1 = leaky(W1·leaky(LN(h)) + b1), emitted bf16 transposed [b][k]
__global__ __launch_bounds__(256) void kHead1(const float* __restrict__ hTall,
                                              const float* __restrict__ lnPS, const float* __restrict__ lnPQ,
                                              const float* __restrict__ ln_g, const float* __restrict__ ln_b,
                                              const unsigned* __restrict__ W1p, const float* __restrict__ b1,
                                              unsigned* __restrict__ h1bfT) {
    int wid = __builtin_amdgcn_readfirstlane((int)blockIdx.x * 4 + ((int)threadIdx.x >> 6));
    int lane = (int)threadIdx.x & 63;
    int t = wid >> 7, g = wid & 127, n0 = g * 2;
    const float* pS = lnPS + (size_t)t * 2048;
    const float* pQ = lnPQ + (size_t)t * 2048;
    float ms = 0.f, qs = 0.f;
    #pragma unroll 8
    for (int i = 0; i < 32; ++i) { ms += pS[i * 64 + lane]; qs += pQ[i * 64 + lane]; }
    float m = ms * (1.f / 512.f);
    float var = qs * (1.f / 512.f) - m * m;
    float rstd = 1.f / sqrtf(var + 1e-5f);
    float mneg = -m * rstd;
    const float* hb = hTall + (size_t)t * NU * 64;
    const unsigned* wb = W1p + (size_t)g * 512;
    float acc0 = 0.f, acc1 = 0.f;
    #pragma unroll 4
    for (int k = 0; k < NU; ++k) {
        float hv = hb[k * 64 + lane];
        float sv = leaky(fmaf(fmaf(hv, rstd, mneg), ln_g[k], ln_b[k]));
        unsigned p = wb[k];
        acc0 = fmaf(lo16(p), sv, acc0);
        acc1 = fmaf(hi16(p), sv, acc1);
    }
    float v0 = leaky(acc0 + b1[n0]);
    float v1 = leaky(acc1 + b1[n0 + 1]);
    h1bfT[((size_t)t * 64 + lane) * 128 + g] = (unsigned)f2bf(v0) | ((unsigned)f2bf(v1) << 16);
}

// MFMA logits: 4695 blocks (18780 waves); wave = (t, m-tile, n-tile), K=256 in 8 MFMA.
__global__ __launch_bounds__(256) void kLogitsMF(const unsigned short* __restrict__ W2bf,
                                                 const unsigned short* __restrict__ h1bfT,
                                                 const float* __restrict__ b2,
                                                 float* __restrict__ lgAll, float* __restrict__ zPm) {
    int wid = __builtin_amdgcn_readfirstlane((int)blockIdx.x * 4 + ((int)threadIdx.x >> 6));
    int lane = (int)threadIdx.x & 63;
    int t = wid / 1252;
    int rem = wid - t * 1252;
    int mt = rem >> 2, ntile = rem & 3;
    int m0 = mt * 16, b0 = ntile * 16;
    int q = lane >> 4, col = lane & 15;
    const unsigned short* aBase = W2bf + (size_t)(m0 + col) * 256 + q * 8;
    const unsigned short* bBase = h1bfT + ((size_t)t * 64 + b0 + col) * 256 + q * 8;
    f32x4 acc = {0.f, 0.f, 0.f, 0.f};
    #pragma unroll
    for (int kk = 0; kk < 8; ++kk) {
        bf16x8 af = *(const bf16x8*)(aBase + kk * 32);
        bf16x8 bf = *(const bf16x8*)(bBase + kk * 32);
        acc = __builtin_amdgcn_mfma_f32_16x16x32_bf16(af, bf, acc, 0, 0, 0);
    }
    float eS = 0.f;
    #pragma unroll
    for (int r = 0; r < 4; ++r) {
        int row = m0 + q * 4 + r;
        if (row < NVOC) {
            float lg = acc[r] + b2[row];
            lgAll[((size_t)t * NVOC + row) * 64 + b0 + col] = lg;
            eS += expf(lg);
        }
    }
    eS += __shfl_xor(eS, 16);
    eS += __shfl_xor(eS, 32);
    if (lane < 16)
        zPm[((size_t)t * 313 + mt) * 64 + b0 + col] = eS;
}

// 60 blocks: combine exp partials (313 per t)
__global__ __launch_bounds__(256) void kZc(const float* __restrict__ zPm, float* __restrict__ zQ) {
    __shared__ float red[256];
    int bid = (int)blockIdx.x, tid = (int)threadIdx.x;
    int t = bid >> 2, qd = bid & 3;
    int lane = tid & 63, w = tid >> 6;
    float p = 0.f;
    for (int ii = w; ii < 79; ii += 4) {
        int i = qd * 79 + ii;
        if (i < 313) p += zPm[((size_t)t * 313 + i) * 64 + lane];
    }
    red[tid] = p;
    __syncthreads();
    if (tid < 64) zQ[bid * 64 + tid] = red[tid] + red[64 + tid] + red[128 + tid] + red[192 + tid];
}

__global__ __launch_bounds__(256) void kOut(const float* __restrict__ lgAll,
                                            const float* __restrict__ zQ, float* __restrict__ out) {
    __shared__ float tile[64 * 65];
    int bid = (int)blockIdx.x;
    int t = bid / 79, nt = bid % 79;
    int n0 = nt * 64;
    int tid = (int)threadIdx.x, lane = tid & 63, w = tid >> 6;
    const float* lg = lgAll + (size_t)t * (NVOC * 64);
    float z = zQ[(t * 4) * 64 + lane] + zQ[(t * 4 + 1) * 64 + lane] +
              zQ[(t * 4 + 2) * 64 + lane] + zQ[(t * 4 + 3) * 64 + lane];
    float invZ = 1.f / z;
    for (int i = 0; i < 16; ++i) {
        int r = w * 16 + i, n = n0 + r;
        if (n < NVOC) tile[r * 65 + lane] = expf(lg[n * 64 + lane]) * invZ;
    }
    __syncthreads();
    for (int i = 0; i < 16; ++i) {
        int b = w * 16 + i;
        int n = n0 + lane;
        if (n < NVOC) out[(size_t)b * (NT * NVOC) + t * NVOC + n] = tile[lane * 65 + b];
    }
}

__global__ __launch_bounds__(256) void kScoresT(const float* __restrict__ wT, float* __restrict__ out) {
    __shared__ float tile[64 * 65];
    int bid = (int)blockIdx.x;
    int t = bid / 6, jt = bid % 6;
    int j0 = jt * 64;
    int tid = (int)threadIdx.x, lane = tid & 63, w = tid >> 6;
    for (int i = 0; i < 16; ++i) {
        int r = w * 16 + i, j = j0 + r;
        if (j < NG) tile[r * 65 + lane] = wT[(size_t)t * (NG * 64) + j * 64 + lane];
    }
    __syncthreads();
    for (int i = 0; i < 16; ++i) {
        int b = w * 16 + i;
        int j = j0 + lane;
        if (j < NG) out[OFF_SCORES + (size_t)b * (NT * NG) + t * NG + j] = tile[lane * 65 + b];
    }
}

// ---------- Launch ----------
extern "C" void kernel_launch(void* const* d_in, const int* in_sizes, int n_in,
                              void* d_out, int out_size, void* d_ws, size_t ws_size,
                              hipStream_t stream) {
    const float* features = (const float*)d_in[0];
    const int*   text     = (const int*)d_in[1];
    const float* a0       = (const float*)d_in[2];
    const float* c0       = (const float*)d_in[3];
    const float* enc_W    = (const float*)d_in[4];
    const float* enc_b    = (const float*)d_in[5];
    const float* enc_g    = (const float*)d_in[6];
    const float* enc_beta = (const float*)d_in[7];
    const float* emb      = (const float*)d_in[8];
    const float* in_w     = (const float*)d_in[9];
    const float* in_b     = (const float*)d_in[10];
    const float* Wih      = (const float*)d_in[11];
    const float* Whh      = (const float*)d_in[12];
    const float* bih      = (const float*)d_in[13];
    const float* bhh      = (const float*)d_in[14];
    const float* ln_g     = (const float*)d_in[15];
    const float* ln_b     = (const float*)d_in[16];
    const float* W1       = (const float*)d_in[17];
    const float* b1       = (const float*)d_in[18];
    const float* W2       = (const float*)d_in[19];
    const float* b2       = (const float*)d_in[20];
    float* out = (float*)d_out;

    float* ws = (float*)d_ws;
    size_t off = 0;
    auto alloc = [&](size_t n) { float* p = ws + off; off += (n + 63) & ~(size_t)63; return p; };
    float* lgAll   = alloc((size_t)NT * NVOC * 64);   // aliased as fX pre-loop
    float* fX      = lgAll;
    float* featT   = alloc((size_t)NG * ND * 64);
    float* xT      = alloc((size_t)NT * NU * 64);
    float* gihxAll = alloc((size_t)NT * 4 * NU * 64);
    unsigned* kf2  = (unsigned*)alloc((size_t)NG * 272 * 64);
    float* wT      = alloc((size_t)NT * NG * 64);
    float* vT      = alloc((size_t)NH * NG * 64);
    float* cS      = alloc((size_t)NH * NG * 64);
    float* fmean   = alloc((size_t)ND * 64);
    float* qmean   = alloc((size_t)NE * 64);
    float* aT0     = alloc((size_t)NU * 64);
    float* cT_     = alloc((size_t)NU * 64);
    float* hTall   = alloc((size_t)NT * NU * 64);
    float* qaT     = alloc((size_t)NE * 64);
    float* ghh     = alloc((size_t)4 * NU * 64);
    float* sevP    = alloc((size_t)720 * 64);
    float* cevP    = alloc((size_t)720 * 64);
    float* ctxP    = alloc((size_t)24 * 2048);
    float* lnPS    = alloc((size_t)NT * 32 * 64);
    float* lnPQ    = alloc((size_t)NT * 32 * 64);
    float* zPm     = alloc((size_t)NT * 313 * 64);
    float* zQ      = alloc((size_t)NT * 4 * 64);
    unsigned* Wqp  = (unsigned*)alloc((size_t)272 * 512);
    unsigned* Whhp = (unsigned*)alloc((size_t)1024 * 512);
    unsigned* Wxp  = (unsigned*)alloc((size_t)1024 * 512);
    unsigned* W1p  = (unsigned*)alloc((size_t)128 * 512);
    unsigned short* W2bf = (unsigned short*)alloc((size_t)5008 * 128);
    unsigned* h1bfT = (unsigned*)alloc((size_t)NT * 64 * 128);

    // weight packing / conversion
    kPack<<<544, 256, 0, stream>>>(in_w, NE, ND, 512, 272 * 512, Wqp);
    kPack<<<2048, 256, 0, stream>>>(Whh, NU, 0, 512, 1024 * 512, Whhp);
    kPack<<<2048, 256, 0, stream>>>(Wih, NE, ND, 512, 1024 * 512, Wxp);
    kPack<<<256, 256, 0, stream>>>(W1, NU, 0, 512, 128 * 512, W1p);
    kCvtW2<<<5008, 256, 0, stream>>>(W2, W2bf);

    k_transpose_feat<<<563, 256, 0, stream>>>(features, fX);
    k_encoder2<<<NG, 256, 0, stream>>>(fX, enc_W, enc_b, enc_g, enc_beta, featT);
    k_init_state<<<16, 256, 0, stream>>>(a0, c0, aT0, cT_);
    k_embed<<<NT, 256, 0, stream>>>(text, emb, xT);
    k_kf<<<3060, 256, 0, stream>>>(featT, in_w, kf2);
    k_featmean<<<8, 256, 0, stream>>>(featT, fmean);
    k_qmean<<<17, 256, 0, stream>>>(fmean, in_w, qmean);
    k_cs<<<180, 256, 0, stream>>>(qmean, kf2, cS);
    k_gihx<<<1920, 256, 0, stream>>>(xT, Wxp, gihxAll);

    for (int t = 0; t < NT; ++t) {
        kA<<<162, 256, 0, stream>>>(aT0, hTall, lnPS, lnPQ, ln_g, ln_b,
                                    Wqp, in_b, Whhp, qaT, ghh, t);
        kB<<<180, 256, 0, stream>>>(qaT, kf2, cS, vT, sevP, cevP);
        kC<<<24, 256, 0, stream>>>(vT, cS, sevP, cevP, featT,
                                   wT + (size_t)t * NG * 64, ctxP);
        kF1<<<32, 256, 0, stream>>>(gihxAll + (size_t)t * 4 * NU * 64, ghh, ctxP, Wih,
                                    bih, bhh, cT_, hTall + (size_t)t * NU * 64,
                                    lnPS + (size_t)t * 2048, lnPQ + (size_t)t * 2048);
    }

    kHead1<<<480, 256, 0, stream>>>(hTall, lnPS, lnPQ, ln_g, ln_b, W1p, b1, h1bfT);
    kLogitsMF<<<4695, 256, 0, stream>>>(W2bf, (const unsigned short*)h1bfT, b2, lgAll, zPm);
    kZc<<<60, 256, 0, stream>>>(zPm, zQ);
    kOut<<<NT * 79, 256, 0, stream>>>(lgAll, zQ, out);
    kScoresT<<<NT * 6, 256, 0, stream>>>(wT, out);
}

// Round 7
// 1467.284 us; speedup vs baseline: 7.5321x; 1.2009x over previous
//
#include <hip/hip_runtime.h>
#include <math.h>

#define NG 360
#define NV 100
#define ND 32
#define NU 512
#define NT 15
#define NVOC 5000
#define NH 8
#define NE 544
#define NHD 68
#define OFF_SCORES 4800000
#define INV_SQRT_HD 0.12126781f
#define CS_SCALE 43.65636f

typedef short bf16x8 __attribute__((ext_vector_type(8)));
typedef float f32x4 __attribute__((ext_vector_type(4)));

__device__ __forceinline__ float leaky(float x) { return x >= 0.f ? x : 0.2f * x; }
__device__ __forceinline__ float sigm(float x) { return 1.f / (1.f + expf(-x)); }
__device__ __forceinline__ unsigned short f2bf(float x) {
    unsigned b = __float_as_uint(x);
    return (unsigned short)((b + 0x7FFFu + ((b >> 16) & 1u)) >> 16);
}
__device__ __forceinline__ float lo16(unsigned p) { return __uint_as_float(p << 16); }
__device__ __forceinline__ float hi16(unsigned p) { return __uint_as_float(p & 0xffff0000u); }

// ---------- Weight prep ----------

// rows 2g,2g+1 -> one uint (bf16 lo/hi)
__global__ __launch_bounds__(256) void kPack(const float* __restrict__ W, int ldw, int col0,
                                             int K, int total, unsigned* __restrict__ outp) {
    int idx = (int)blockIdx.x * 256 + (int)threadIdx.x;
    if (idx >= total) return;
    int g = idx / K, k = idx - g * K;
    float w0 = W[(size_t)(2 * g) * ldw + col0 + k];
    float w1 = W[(size_t)(2 * g + 1) * ldw + col0 + k];
    outp[idx] = (unsigned)f2bf(w0) | ((unsigned)f2bf(w1) << 16);
}

// plain bf16 row-major [rows][K] from fp32 (ldw stride, col0 offset)
__global__ __launch_bounds__(256) void kCvt(const float* __restrict__ W, int ldw, int col0,
                                            int K, int total, unsigned short* __restrict__ o) {
    int idx = (int)blockIdx.x * 256 + (int)threadIdx.x;
    if (idx >= total) return;
    int r = idx / K, k = idx - r * K;
    o[idx] = f2bf(W[(size_t)r * ldw + col0 + k]);
}

// W2 -> bf16 [5008][256] (8 pad rows zeroed)
__global__ __launch_bounds__(256) void kCvtW2(const float* __restrict__ W2,
                                              unsigned short* __restrict__ W2bf) {
    int idx = (int)blockIdx.x * 256 + (int)threadIdx.x;
    if (idx < NVOC * 256) W2bf[idx] = f2bf(W2[idx]);
    else if (idx < 5008 * 256) W2bf[idx] = 0;
}

// ---------- Precompute ----------

__global__ void k_transpose_feat(const float* __restrict__ features, float* __restrict__ fX) {
    __shared__ float tile[64 * 65];
    int c0 = (int)blockIdx.x * 64;
    int tl = (int)threadIdx.x;
    int c = tl & 63, q0 = tl >> 6;
    for (int i = 0; i < 16; ++i) {
        int b = q0 + (i << 2);
        int col = c0 + c;
        float v = (col < NG * NV) ? features[b * (NG * NV) + col] : 0.f;
        tile[c * 65 + b] = v;
    }
    __syncthreads();
    int b2 = tl & 63, cr = tl >> 6;
    for (int i = 0; i < 16; ++i) {
        int c2 = cr + (i << 2);
        int col = c0 + c2;
        if (col < NG * NV) fX[col * 64 + b2] = tile[c2 * 65 + b2];
    }
}

// encoder: writes featT [(g*32+d)][b] and featB [b][g][d]
__global__ __launch_bounds__(256) void k_encoder2(
        const float* __restrict__ fX, const float* __restrict__ enc_W,
        const float* __restrict__ enc_b, const float* __restrict__ enc_g,
        const float* __restrict__ enc_beta, float* __restrict__ featT,
        float* __restrict__ featB) {
    __shared__ float fxs[6400];
    __shared__ float ps[256], pq[256];
    int g = (int)blockIdx.x, tid = (int)threadIdx.x;
    #pragma unroll
    for (int k = 0; k < 25; ++k) fxs[tid + k * 256] = fX[g * 6400 + tid + k * 256];
    __syncthreads();
    int lane = tid & 63, w = tid >> 6, d0 = w * 8;
    float acc[8];
    #pragma unroll
    for (int j = 0; j < 8; ++j) acc[j] = enc_b[g * 32 + d0 + j];
    const float* wb = enc_W + g * 3200 + d0 * 100;
    #pragma unroll 4
    for (int v = 0; v < 100; ++v) {
        float fv = fxs[v * 64 + lane];
        #pragma unroll
        for (int j = 0; j < 8; ++j) acc[j] += fv * wb[j * 100 + v];
    }
    float sm = 0.f, sq = 0.f;
    #pragma unroll
    for (int j = 0; j < 8; ++j) { sm += acc[j]; sq += acc[j] * acc[j]; }
    ps[tid] = sm; pq[tid] = sq;
    __syncthreads();
    float m = (ps[lane] + ps[64 + lane] + ps[128 + lane] + ps[192 + lane]) * (1.f / 32.f);
    float q = (pq[lane] + pq[64 + lane] + pq[128 + lane] + pq[192 + lane]);
    float var = q * (1.f / 32.f) - m * m;
    float rstd = 1.f / sqrtf(var + 1e-5f);
    #pragma unroll
    for (int j = 0; j < 8; ++j) {
        int d = d0 + j;
        float x = (acc[j] - m) * rstd * enc_g[d] + enc_beta[d];
        x = leaky(x);
        featT[(g * 32 + d) * 64 + lane] = x;
        featB[((size_t)lane * NG + g) * 32 + d] = x;
    }
}

__global__ void k_init_state(const float* __restrict__ a0, const float* __restrict__ c0,
                             float* __restrict__ aT0, float* __restrict__ cT) {
    __shared__ float tile[64 * 65];
    int which = (int)blockIdx.x >> 3;
    int t0 = ((int)blockIdx.x & 7) * 64;
    const float* src = which ? c0 : a0;
    int tl = (int)threadIdx.x;
    int c = tl & 63, q0 = tl >> 6;
    for (int i = 0; i < 16; ++i) {
        int b = q0 + (i << 2);
        tile[c * 65 + b] = src[b * NU + t0 + c];
    }
    __syncthreads();
    int b2 = tl & 63, cr = tl >> 6;
    for (int i = 0; i < 16; ++i) {
        int c2 = cr + (i << 2);
        float v = tile[c2 * 65 + b2];
        int idx = (t0 + c2) * 64 + b2;
        if (which) cT[idx] = v;
        else aT0[idx] = v;
    }
}

// xbf[(t*64+b)][u] bf16
__global__ void kEmbed(const int* __restrict__ text, const float* __restrict__ emb,
                       unsigned short* __restrict__ xbf) {
    int t = (int)blockIdx.x, tid = (int)threadIdx.x;
    int b = tid >> 2, seg = (tid & 3) * 128;
    int row = text[b * NT + t];
    const float* er = emb + (size_t)row * NU;
    unsigned short* dst = xbf + ((size_t)t * 64 + b) * 512;
    for (int i = 0; i < 128; ++i) dst[seg + i] = f2bf(er[seg + i]);
}

__global__ void k_featmean(const float* __restrict__ featT, float* __restrict__ fmean) {
    int wid = __builtin_amdgcn_readfirstlane((int)blockIdx.x * 4 + ((int)threadIdx.x >> 6));
    int lane = (int)threadIdx.x & 63;
    if (wid >= ND) return;
    float s = 0.f;
    for (int g = 0; g < NG; ++g) s += featT[(g * ND + wid) * 64 + lane];
    fmean[wid * 64 + lane] = s * (1.f / 360.f);
}

__global__ void k_qmean(const float* __restrict__ fmean, const float* __restrict__ in_w,
                        float* __restrict__ qmean) {
    int wid = __builtin_amdgcn_readfirstlane((int)blockIdx.x * 4 + ((int)threadIdx.x >> 6));
    int lane = (int)threadIdx.x & 63;
    if (wid >= 68) return;
    int e0 = wid * 8;
    float acc[8];
    #pragma unroll
    for (int jj = 0; jj < 8; ++jj) acc[jj] = 0.f;
    #pragma unroll 4
    for (int d = 0; d < ND; ++d) {
        float fv = fmean[d * 64 + lane];
        #pragma unroll
        for (int jj = 0; jj < 8; ++jj) acc[jj] += fv * in_w[(e0 + jj) * NE + d];
    }
    #pragma unroll
    for (int jj = 0; jj < 8; ++jj) qmean[(e0 + jj) * 64 + lane] = acc[jj];
}

// m[b][h*32+d'] = sum_{d<68} Wk[h*68+d][d'] * qa[(h*68+d)][b]   (8 blocks, 32 waves)
__global__ __launch_bounds__(256) void kM(const float* __restrict__ qa,
                                          const float* __restrict__ in_w,
                                          float* __restrict__ m) {
    int wid = __builtin_amdgcn_readfirstlane((int)blockIdx.x * 4 + ((int)threadIdx.x >> 6));
    int lane = (int)threadIdx.x & 63;
    int h = wid >> 2, dg = (wid & 3) * 8;
    float acc[8] = {0.f, 0.f, 0.f, 0.f, 0.f, 0.f, 0.f, 0.f};
    for (int d = 0; d < NHD; ++d) {
        float qv = qa[(h * NHD + d) * 64 + lane];
        const float* wr = in_w + (size_t)(NE + h * NHD + d) * NE + dg;
        #pragma unroll
        for (int i = 0; i < 8; ++i) acc[i] = fmaf(qv, wr[i], acc[i]);
    }
    #pragma unroll
    for (int i = 0; i < 8; ++i) m[(size_t)lane * 256 + h * 32 + dg + i] = acc[i];
}

// cSb[b][h][j] = CS_SCALE * feat[b,j]·mq[b,h]   (96 blocks, lane = j)
__global__ __launch_bounds__(256) void kCS(const float* __restrict__ mq,
                                           const float* __restrict__ featB,
                                           float* __restrict__ cSb) {
    int wid = __builtin_amdgcn_readfirstlane((int)blockIdx.x * 4 + ((int)threadIdx.x >> 6));
    int lane = (int)threadIdx.x & 63;
    int b = wid / 6, jt = wid % 6;
    int j = jt * 64 + lane;
    bool valid = j < NG;
    int jc = valid ? j : 0;
    const float* mb = mq + (size_t)b * 256;
    const float* fb = featB + ((size_t)b * NG + jc) * 32;
    float v[8] = {0.f, 0.f, 0.f, 0.f, 0.f, 0.f, 0.f, 0.f};
    #pragma unroll
    for (int dc = 0; dc < 32; dc += 4) {
        float4 f = *(const float4*)(fb + dc);
        #pragma unroll
        for (int h = 0; h < 8; ++h) {
            v[h] = fmaf(f.x, mb[h * 32 + dc], v[h]);
            v[h] = fmaf(f.y, mb[h * 32 + dc + 1], v[h]);
            v[h] = fmaf(f.z, mb[h * 32 + dc + 2], v[h]);
            v[h] = fmaf(f.w, mb[h * 32 + dc + 3], v[h]);
        }
    }
    if (valid) {
        #pragma unroll
        for (int h = 0; h < 8; ++h)
            cSb[(size_t)b * 2880 + h * NG + j] = v[h] * CS_SCALE;
    }
}

// gihxAll[t][n][b] via MFMA: M=2048 (Wih rows), cols = t*64+b, K=512. 1920 blocks.
__global__ __launch_bounds__(256) void kGihxMF(const unsigned short* __restrict__ Wihx,
                                               const unsigned short* __restrict__ xbf,
                                               float* __restrict__ gihxAll) {
    int wid = __builtin_amdgcn_readfirstlane((int)blockIdx.x * 4 + ((int)threadIdx.x >> 6));
    int lane = (int)threadIdx.x & 63;
    int mt = wid / 60, nt = wid % 60;
    int m0 = mt * 16, col = lane & 15, q = lane >> 4;
    const unsigned short* aB = Wihx + (size_t)(m0 + col) * 512 + q * 8;
    const unsigned short* bB = xbf + (size_t)(nt * 16 + col) * 512 + q * 8;
    f32x4 acc = {0.f, 0.f, 0.f, 0.f};
    #pragma unroll
    for (int kk = 0; kk < 16; ++kk) {
        bf16x8 af = *(const bf16x8*)(aB + kk * 32);
        bf16x8 bf = *(const bf16x8*)(bB + kk * 32);
        acc = __builtin_amdgcn_mfma_f32_16x16x32_bf16(af, bf, acc, 0, 0, 0);
    }
    int gcol = nt * 16 + col, t = gcol >> 6, b = gcol & 63;
    float* dst = gihxAll + (size_t)t * (4 * NU * 64);
    #pragma unroll
    for (int r = 0; r < 4; ++r) {
        int row = m0 + q * 4 + r;
        dst[row * 64 + b] = acc[r];
    }
}

// ---------- Per-step ----------

// 162 blocks: wid<136 qa (4 rows), else ghh (4 rows). LN of h(t-1) folded.
__global__ __launch_bounds__(256) void kA(
        const float* __restrict__ aT0, const float* __restrict__ hTall,
        const float* __restrict__ lnPS, const float* __restrict__ lnPQ,
        const float* __restrict__ ln_g, const float* __restrict__ ln_b,
        const unsigned* __restrict__ Wqp, const float* __restrict__ in_b,
        const unsigned* __restrict__ Whhp,
        float* __restrict__ qaT, float* __restrict__ ghh, int t) {
    int wid = __builtin_amdgcn_readfirstlane((int)blockIdx.x * 4 + ((int)threadIdx.x >> 6));
    int lane = (int)threadIdx.x & 63;
    float rstd = 1.f, mneg = 0.f;
    const float* src = aT0;
    if (t > 0) {
        const float* pS = lnPS + (size_t)(t - 1) * 2048;
        const float* pQ = lnPQ + (size_t)(t - 1) * 2048;
        float ms = 0.f, qs = 0.f;
        #pragma unroll 8
        for (int i = 0; i < 32; ++i) { ms += pS[i * 64 + lane]; qs += pQ[i * 64 + lane]; }
        float m = ms * (1.f / 512.f);
        float var = qs * (1.f / 512.f) - m * m;
        rstd = 1.f / sqrtf(var + 1e-5f);
        mneg = -m * rstd;
        src = hTall + (size_t)(t - 1) * (NU * 64);
    }
    float a0 = 0.f, a1 = 0.f, a2 = 0.f, a3 = 0.f;
    const unsigned *wb0, *wb1;
    int n0;
    bool isQ = wid < 136;
    if (isQ) { n0 = wid * 4; wb0 = Wqp + (size_t)(2 * wid) * 512; }
    else { n0 = (wid - 136) * 4; wb0 = Whhp + (size_t)(2 * (wid - 136)) * 512; }
    wb1 = wb0 + 512;
    if (t == 0) {
        #pragma unroll 4
        for (int k = 0; k < NU; ++k) {
            float av = src[k * 64 + lane];
            unsigned p0 = wb0[k], p1 = wb1[k];
            a0 = fmaf(lo16(p0), av, a0);
            a1 = fmaf(hi16(p0), av, a1);
            a2 = fmaf(lo16(p1), av, a2);
            a3 = fmaf(hi16(p1), av, a3);
        }
    } else {
        #pragma unroll 4
        for (int k = 0; k < NU; ++k) {
            float hv = src[k * 64 + lane];
            float av = fmaf(fmaf(hv, rstd, mneg), ln_g[k], ln_b[k]);
            unsigned p0 = wb0[k], p1 = wb1[k];
            a0 = fmaf(lo16(p0), av, a0);
            a1 = fmaf(hi16(p0), av, a1);
            a2 = fmaf(lo16(p1), av, a2);
            a3 = fmaf(hi16(p1), av, a3);
        }
    }
    if (isQ) {
        qaT[n0 * 64 + lane] = a0 + in_b[n0];
        qaT[(n0 + 1) * 64 + lane] = a1 + in_b[n0 + 1];
        qaT[(n0 + 2) * 64 + lane] = a2 + in_b[n0 + 2];
        qaT[(n0 + 3) * 64 + lane] = a3 + in_b[n0 + 3];
    } else {
        ghh[n0 * 64 + lane] = a0;
        ghh[(n0 + 1) * 64 + lane] = a1;
        ghh[(n0 + 2) * 64 + lane] = a2;
        ghh[(n0 + 3) * 64 + lane] = a3;
    }
}

// 96 blocks, lane = j: e=exp(feat·m/√68), partials; evb[b][h][j]
__global__ __launch_bounds__(256) void kB(
        const float* __restrict__ m, const float* __restrict__ featB,
        const float* __restrict__ cSb,
        float* __restrict__ evb, float* __restrict__ sevP, float* __restrict__ cevP) {
    int wid = __builtin_amdgcn_readfirstlane((int)blockIdx.x * 4 + ((int)threadIdx.x >> 6));
    int lane = (int)threadIdx.x & 63;
    int b = wid / 6, jt = wid % 6;
    int j = jt * 64 + lane;
    bool valid = j < NG;
    int jc = valid ? j : 0;
    const float* mb = m + (size_t)b * 256;
    const float* fb = featB + ((size_t)b * NG + jc) * 32;
    float v[8] = {0.f, 0.f, 0.f, 0.f, 0.f, 0.f, 0.f, 0.f};
    #pragma unroll
    for (int dc = 0; dc < 32; dc += 4) {
        float4 f = *(const float4*)(fb + dc);
        #pragma unroll
        for (int h = 0; h < 8; ++h) {
            v[h] = fmaf(f.x, mb[h * 32 + dc], v[h]);
            v[h] = fmaf(f.y, mb[h * 32 + dc + 1], v[h]);
            v[h] = fmaf(f.z, mb[h * 32 + dc + 2], v[h]);
            v[h] = fmaf(f.w, mb[h * 32 + dc + 3], v[h]);
        }
    }
    float eS[8], eC[8];
    #pragma unroll
    for (int h = 0; h < 8; ++h) {
        float e = valid ? expf(v[h] * INV_SQRT_HD) : 0.f;
        float c = valid ? cSb[(size_t)b * 2880 + h * NG + j] : 0.f;
        if (valid) evb[(size_t)b * 2880 + h * NG + j] = e;
        eS[h] = e; eC[h] = c * e;
    }
    #pragma unroll
    for (int h = 0; h < 8; ++h) {
        #pragma unroll
        for (int off = 32; off > 0; off >>= 1) {
            eS[h] += __shfl_xor(eS[h], off);
            eC[h] += __shfl_xor(eC[h], off);
        }
    }
    if (lane == 0) {
        #pragma unroll
        for (int h = 0; h < 8; ++h) {
            sevP[b * 48 + jt * 8 + h] = eS[h];
            cevP[b * 48 + jt * 8 + h] = eC[h];
        }
    }
}

// 64 blocks (one per b): combine partials, W -> out scores + complete ctx[d][b].
__global__ __launch_bounds__(256) void kC(
        const float* __restrict__ evb, const float* __restrict__ cSb,
        const float* __restrict__ sevP, const float* __restrict__ cevP,
        const float* __restrict__ featB,
        float* __restrict__ out, float* __restrict__ ctx, int t) {
    __shared__ float SevL[8], CevL[8], WL[360], sbuf[48], cbuf[48], cpart[256];
    int b = (int)blockIdx.x, tid = (int)threadIdx.x;
    if (tid < 48) { sbuf[tid] = sevP[b * 48 + tid]; cbuf[tid] = cevP[b * 48 + tid]; }
    __syncthreads();
    if (tid < 8) {
        float s = 0.f, c = 0.f;
        #pragma unroll
        for (int jt = 0; jt < 6; ++jt) { s += sbuf[jt * 8 + tid]; c += cbuf[jt * 8 + tid]; }
        SevL[tid] = s; CevL[tid] = c;
    }
    __syncthreads();
    float invS[8], cevM[8];
    #pragma unroll
    for (int h = 0; h < 8; ++h) {
        float iv = 1.f / SevL[h];
        invS[h] = iv;
        cevM[h] = CevL[h] * iv;
    }
    for (int j = tid; j < NG; j += 256) {
        float acc = 0.f;
        #pragma unroll
        for (int h = 0; h < 8; ++h) {
            float e = evb[(size_t)b * 2880 + h * NG + j];
            float c = cSb[(size_t)b * 2880 + h * NG + j];
            acc += e * invS[h] * (1.f + (c - cevM[h]) * (1.f / 360.f));
        }
        float W = acc * 0.125f;
        WL[j] = W;
        out[OFF_SCORES + (size_t)b * (NT * NG) + t * NG + j] = W;
    }
    __syncthreads();
    int d = tid & 31, sl = tid >> 5;
    float a = 0.f;
    for (int i = 0; i < 45; ++i) {
        int j = sl * 45 + i;
        a += WL[j] * featB[((size_t)b * NG + j) * 32 + d];
    }
    cpart[tid] = a;
    __syncthreads();
    if (tid < 32) {
        float s = 0.f;
        #pragma unroll
        for (int ss = 0; ss < 8; ++ss) s += cpart[ss * 32 + tid];
        ctx[tid * 64 + b] = s;
    }
}

// 32 blocks (16 u each): gates + cell + h + LN partials. ctx read directly.
__global__ __launch_bounds__(256) void kF1(
        const float* __restrict__ gihxT, const float* __restrict__ ghh,
        const float* __restrict__ ctx, const float* __restrict__ Wih,
        const float* __restrict__ bih, const float* __restrict__ bhh,
        float* __restrict__ cT, float* __restrict__ hDst,
        float* __restrict__ lnPS, float* __restrict__ lnPQ) {
    __shared__ float rS[256], rQ[256];
    int tid = (int)threadIdx.x, bid = (int)blockIdx.x;
    int lane = tid & 63, w = tid >> 6;
    float cx[32];
    #pragma unroll 8
    for (int d = 0; d < 32; ++d) cx[d] = ctx[d * 64 + lane];
    int u0 = bid * 16 + w * 4;
    float ssum = 0.f, qsum = 0.f;
    for (int i = 0; i < 4; ++i) {
        int u = u0 + i;
        float g4[4];
        #pragma unroll
        for (int q = 0; q < 4; ++q) {
            int n = q * NU + u;
            float gv = gihxT[n * 64 + lane] + ghh[n * 64 + lane] + bih[n] + bhh[n];
            const float* wr = Wih + (size_t)n * NE;
            #pragma unroll
            for (int d = 0; d < 32; ++d) gv += cx[d] * wr[d];
            g4[q] = gv;
        }
        float ig = sigm(g4[0]), fg = sigm(g4[1]), gg = tanhf(g4[2]), og = sigm(g4[3]);
        float cn = fg * cT[u * 64 + lane] + ig * gg;
        cT[u * 64 + lane] = cn;
        float hv = og * tanhf(cn);
        hDst[u * 64 + lane] = hv;
        ssum += hv; qsum += hv * hv;
    }
    rS[tid] = ssum; rQ[tid] = qsum;
    __syncthreads();
    if (tid < 64) {
        lnPS[bid * 64 + tid] = rS[tid] + rS[64 + tid] + rS[128 + tid] + rS[192 + tid];
        lnPQ[bid * 64 + tid] = rQ[tid] + rQ[64 + tid] + rQ[128 + tid] + rQ[192 + tid];
    }
}

// ---------- Post-loop head ----------

// 480 blocks: h1 = leaky(W1·leaky(LN(h)) + b1), bf16 transposed [t*64+b][k]
__global__ __launch_bounds__(256) void kHead1(const float* __restrict__ hTall,
                                              const float* __restrict__ lnPS, const float* __restrict__ lnPQ,
                                              const float* __restrict__ ln_g, const float* __restrict__ ln_b,
                                              const unsigned* __restrict__ W1p, const float* __restrict__ b1,
                                              unsigned* __restrict__ h1bfT) {
    int wid = __builtin_amdgcn_readfirstlane((int)blockIdx.x * 4 + ((int)threadIdx.x >> 6));
    int lane = (int)threadIdx.x & 63;
    int t = wid >> 7, g = wid & 127, n0 = g * 2;
    const float* pS = lnPS + (size_t)t * 2048;
    const float* pQ = lnPQ + (size_t)t * 2048;
    float ms = 0.f, qs = 0.f;
    #pragma unroll 8
    for (int i = 0; i < 32; ++i) { ms += pS[i * 64 + lane]; qs += pQ[i * 64 + lane]; }
    float m = ms * (1.f / 512.f);
    float var = qs * (1.f / 512.f) - m * m;
    float rstd = 1.f / sqrtf(var + 1e-5f);
    float mneg = -m * rstd;
    const float* hb = hTall + (size_t)t * NU * 64;
    const unsigned* wb = W1p + (size_t)g * 512;
    float acc0 = 0.f, acc1 = 0.f;
    #pragma unroll 4
    for (int k = 0; k < NU; ++k) {
        float hv = hb[k * 64 + lane];
        float sv = leaky(fmaf(fmaf(hv, rstd, mneg), ln_g[k], ln_b[k]));
        unsigned p = wb[k];
        acc0 = fmaf(lo16(p), sv, acc0);
        acc1 = fmaf(hi16(p), sv, acc1);
    }
    float v0 = leaky(acc0 + b1[n0]);
    float v1 = leaky(acc1 + b1[n0 + 1]);
    h1bfT[((size_t)t * 64 + lane) * 128 + g] = (unsigned)f2bf(v0) | ((unsigned)f2bf(v1) << 16);
}

// MFMA logits: 4695 blocks
__global__ __launch_bounds__(256) void kLogitsMF(const unsigned short* __restrict__ W2bf,
                                                 const unsigned short* __restrict__ h1bfT,
                                                 const float* __restrict__ b2,
                                                 float* __restrict__ lgAll, float* __restrict__ zPm) {
    int wid = __builtin_amdgcn_readfirstlane((int)blockIdx.x * 4 + ((int)threadIdx.x >> 6));
    int lane = (int)threadIdx.x & 63;
    int t = wid / 1252;
    int rem = wid - t * 1252;
    int mt = rem >> 2, ntile = rem & 3;
    int m0 = mt * 16, b0 = ntile * 16;
    int q = lane >> 4, col = lane & 15;
    const unsigned short* aBase = W2bf + (size_t)(m0 + col) * 256 + q * 8;
    const unsigned short* bBase = h1bfT + ((size_t)t * 64 + b0 + col) * 256 + q * 8;
    f32x4 acc = {0.f, 0.f, 0.f, 0.f};
    #pragma unroll
    for (int kk = 0; kk < 8; ++kk) {
        bf16x8 af = *(const bf16x8*)(aBase + kk * 32);
        bf16x8 bf = *(const bf16x8*)(bBase + kk * 32);
        acc = __builtin_amdgcn_mfma_f32_16x16x32_bf16(af, bf, acc, 0, 0, 0);
    }
    float eS = 0.f;
    #pragma unroll
    for (int r = 0; r < 4; ++r) {
        int row = m0 + q * 4 + r;
        if (row < NVOC) {
            float lg = acc[r] + b2[row];
            lgAll[((size_t)t * NVOC + row) * 64 + b0 + col] = lg;
            eS += expf(lg);
        }
    }
    eS += __shfl_xor(eS, 16);
    eS += __shfl_xor(eS, 32);
    if (lane < 16)
        zPm[((size_t)t * 313 + mt) * 64 + b0 + col] = eS;
}

__global__ __launch_bounds__(256) void kZc(const float* __restrict__ zPm, float* __restrict__ zQ) {
    __shared__ float red[256];
    int bid = (int)blockIdx.x, tid = (int)threadIdx.x;
    int t = bid >> 2, qd = bid & 3;
    int lane = tid & 63, w = tid >> 6;
    float p = 0.f;
    for (int ii = w; ii < 79; ii += 4) {
        int i = qd * 79 + ii;
        if (i < 313) p += zPm[((size_t)t * 313 + i) * 64 + lane];
    }
    red[tid] = p;
    __syncthreads();
    if (tid < 64) zQ[bid * 64 + tid] = red[tid] + red[64 + tid] + red[128 + tid] + red[192 + tid];
}

__global__ __launch_bounds__(256) void kOut(const float* __restrict__ lgAll,
                                            const float* __restrict__ zQ, float* __restrict__ out) {
    __shared__ float tile[64 * 65];
    int bid = (int)blockIdx.x;
    int t = bid / 79, nt = bid % 79;
    int n0 = nt * 64;
    int tid = (int)threadIdx.x, lane = tid & 63, w = tid >> 6;
    const float* lg = lgAll + (size_t)t * (NVOC * 64);
    float z = zQ[(t * 4) * 64 + lane] + zQ[(t * 4 + 1) * 64 + lane] +
              zQ[(t * 4 + 2) * 64 + lane] + zQ[(t * 4 + 3) * 64 + lane];
    float invZ = 1.f / z;
    for (int i = 0; i < 16; ++i) {
        int r = w * 16 + i, n = n0 + r;
        if (n < NVOC) tile[r * 65 + lane] = expf(lg[n * 64 + lane]) * invZ;
    }
    __syncthreads();
    for (int i = 0; i < 16; ++i) {
        int b = w * 16 + i;
        int n = n0 + lane;
        if (n < NVOC) out[(size_t)b * (NT * NVOC) + t * NVOC + n] = tile[lane * 65 + b];
    }
}

// ---------- Launch ----------
extern "C" void kernel_launch(void* const* d_in, const int* in_sizes, int n_in,
                              void* d_out, int out_size, void* d_ws, size_t ws_size,
                              hipStream_t stream) {
    const float* features = (const float*)d_in[0];
    const int*   text     = (const int*)d_in[1];
    const float* a0       = (const float*)d_in[2];
    const float* c0       = (const float*)d_in[3];
    const float* enc_W    = (const float*)d_in[4];
    const float* enc_b    = (const float*)d_in[5];
    const float* enc_g    = (const float*)d_in[6];
    const float* enc_beta = (const float*)d_in[7];
    const float* emb      = (const float*)d_in[8];
    const float* in_w     = (const float*)d_in[9];
    const float* in_b     = (const float*)d_in[10];
    const float* Wih      = (const float*)d_in[11];
    const float* Whh      = (const float*)d_in[12];
    const float* bih      = (const float*)d_in[13];
    const float* bhh      = (const float*)d_in[14];
    const float* ln_g     = (const float*)d_in[15];
    const float* ln_b     = (const float*)d_in[16];
    const float* W1       = (const float*)d_in[17];
    const float* b1       = (const float*)d_in[18];
    const float* W2       = (const float*)d_in[19];
    const float* b2       = (const float*)d_in[20];
    float* out = (float*)d_out;

    float* ws = (float*)d_ws;
    size_t off = 0;
    auto alloc = [&](size_t n) { float* p = ws + off; off += (n + 63) & ~(size_t)63; return p; };
    float* lgAll   = alloc((size_t)NT * NVOC * 64);   // aliased as fX pre-loop
    float* fX      = lgAll;
    float* featT   = alloc((size_t)NG * ND * 64);
    float* featB   = alloc((size_t)64 * NG * ND);
    float* gihxAll = alloc((size_t)NT * 4 * NU * 64);
    float* fmean   = alloc((size_t)ND * 64);
    float* qmean   = alloc((size_t)NE * 64);
    float* mq      = alloc((size_t)64 * 256);
    float* mstep   = alloc((size_t)64 * 256);
    float* cSb     = alloc((size_t)64 * NH * NG);
    float* evb     = alloc((size_t)64 * NH * NG);
    float* sevP    = alloc((size_t)64 * 48);
    float* cevP    = alloc((size_t)64 * 48);
    float* aT0     = alloc((size_t)NU * 64);
    float* cT_     = alloc((size_t)NU * 64);
    float* hTall   = alloc((size_t)NT * NU * 64);
    float* qaT     = alloc((size_t)NE * 64);
    float* ghh     = alloc((size_t)4 * NU * 64);
    float* ctx     = alloc((size_t)ND * 64);
    float* lnPS    = alloc((size_t)NT * 32 * 64);
    float* lnPQ    = alloc((size_t)NT * 32 * 64);
    float* zPm     = alloc((size_t)NT * 313 * 64);
    float* zQ      = alloc((size_t)NT * 4 * 64);
    unsigned* Wqp  = (unsigned*)alloc((size_t)272 * 512);
    unsigned* Whhp = (unsigned*)alloc((size_t)1024 * 512);
    unsigned* W1p  = (unsigned*)alloc((size_t)128 * 512);
    unsigned short* Wihx = (unsigned short*)alloc((size_t)2048 * 256);
    unsigned short* xbf  = (unsigned short*)alloc((size_t)960 * 256);
    unsigned short* W2bf = (unsigned short*)alloc((size_t)5008 * 128);
    unsigned* h1bfT = (unsigned*)alloc((size_t)NT * 64 * 128);

    // weight prep
    kPack<<<544, 256, 0, stream>>>(in_w, NE, ND, 512, 272 * 512, Wqp);
    kPack<<<2048, 256, 0, stream>>>(Whh, NU, 0, 512, 1024 * 512, Whhp);
    kPack<<<256, 256, 0, stream>>>(W1, NU, 0, 512, 128 * 512, W1p);
    kCvt<<<4096, 256, 0, stream>>>(Wih, NE, ND, 512, 2048 * 512, Wihx);
    kCvtW2<<<5008, 256, 0, stream>>>(W2, W2bf);

    // precompute
    k_transpose_feat<<<563, 256, 0, stream>>>(features, fX);
    k_encoder2<<<NG, 256, 0, stream>>>(fX, enc_W, enc_b, enc_g, enc_beta, featT, featB);
    k_init_state<<<16, 256, 0, stream>>>(a0, c0, aT0, cT_);
    kEmbed<<<NT, 256, 0, stream>>>(text, emb, xbf);
    k_featmean<<<8, 256, 0, stream>>>(featT, fmean);
    k_qmean<<<17, 256, 0, stream>>>(fmean, in_w, qmean);
    kM<<<8, 256, 0, stream>>>(qmean, in_w, mq);
    kCS<<<96, 256, 0, stream>>>(mq, featB, cSb);
    kGihxMF<<<1920, 256, 0, stream>>>(Wihx, xbf, gihxAll);

    for (int t = 0; t < NT; ++t) {
        kA<<<162, 256, 0, stream>>>(aT0, hTall, lnPS, lnPQ, ln_g, ln_b,
                                    Wqp, in_b, Whhp, qaT, ghh, t);
        kM<<<8, 256, 0, stream>>>(qaT, in_w, mstep);
        kB<<<96, 256, 0, stream>>>(mstep, featB, cSb, evb, sevP, cevP);
        kC<<<64, 256, 0, stream>>>(evb, cSb, sevP, cevP, featB, out, ctx, t);
        kF1<<<32, 256, 0, stream>>>(gihxAll + (size_t)t * 4 * NU * 64, ghh, ctx, Wih,
                                    bih, bhh, cT_, hTall + (size_t)t * NU * 64,
                                    lnPS + (size_t)t * 2048, lnPQ + (size_t)t * 2048);
    }

    kHead1<<<480, 256, 0, stream>>>(hTall, lnPS, lnPQ, ln_g, ln_b, W1p, b1, h1bfT);
    kLogitsMF<<<4695, 256, 0, stream>>>(W2bf, (const unsigned short*)h1bfT, b2, lgAll, zPm);
    kZc<<<60, 256, 0, stream>>>(zPm, zQ);
    kOut<<<NT * 79, 256, 0, stream>>>(lgAll, zQ, out);
}